// Round 4
// baseline (278.237 us; speedup 1.0000x reference)
//
#include <hip/hip_runtime.h>
#include <hip/hip_bf16.h>

// MHA: B=2, S=2048, D=1024, H=16, HD=64. fp32 in, fp32 out.
// Swizzled bf16 inter-kernel layouts (16B blocks) so all staging is contiguous DMA:
//   A/W swizzle ([R][K=1024]): block g=((r>>7)*128+(k>>3))*128+(r&127)
//   K_sw/V_sw: block g=((bh*32+kt)*8+kc)*64+row
// ws: [0,8)MB Qb [B,H,S,HD] | [8,16) K_sw | [16,24) V_sw | [24,32) Wqt/Wkt/Wvt (2MB each)
//     ctx_sw overlays [24,32) after QKV GEMM; Wot overlays [0,2) after fattn.
// Q-proj scale folds 1/sqrt(HD)*log2(e) so fattn uses native exp2.
// R8 post-mortem: global_load_lds global address must be PER-LANE.
// R9: fattn 4 waves x 32q, 32x32x16 MFMA, swapped QK^T, cvt_pk+permlane32_swap P-frags.
//     Bank conflicts 1.05M -> 0 but dur 75->70us only: latency-bound.
// R10: PV software-pipelined one tile behind: NO effect (70->73us, MfmaUtil still 20%).
//     Lesson: waves are barrier-locked into the same phase; within-wave scheduling
//     is not the constraint. VALUBusy 48% x 73us => ~35us VALU floor; >50% stall.
// R11: fattn LDS/barrier-FREE. K/V frags are per-lane coalesced dwordx4 in the swizzled
//     layout, so each wave loads its own frags to registers (K 1 tile ahead, V at tile
//     top). Waves free-run staggered; compiler emits counted vmcnt for reg loads.
//     Cost: 4x redundant L2 reads -> bijective XCD swizzle (4 heads/XCD, 2MB per L2).
// R12: infra failure on R11 run (container died twice, no counters). FA_TILE macro ->
//     __forceinline__ function (compile-risk hardening); logic unchanged. Addressing
//     re-audited: frag elem off = (bh*32+kt)*4096 + kc*512 + row*8, in-bounds incl.
//     the (kt+1)&31 prefetch wrap.

typedef short s16x8 __attribute__((ext_vector_type(8)));
typedef float f32x4v __attribute__((ext_vector_type(4)));
typedef float f32x16v __attribute__((ext_vector_type(16)));
typedef unsigned int u32x4v __attribute__((ext_vector_type(4)));

__device__ inline unsigned short f2bf(float f) {   // RNE (proven R2-R6)
    union { float f; unsigned int i; } x; x.f = f;
    unsigned int r = x.i + 0x7FFFu + ((x.i >> 16) & 1u);
    return (unsigned short)(r >> 16);
}
__device__ inline unsigned int pkbf(float lo, float hi) {  // lo16=bf(lo), hi16=bf(hi)
    return (unsigned int)f2bf(lo) | ((unsigned int)f2bf(hi) << 16);
}

// async global->LDS, 16B/lane. Global address PER-LANE; LDS base wave-uniform,
// HW writes base + lane*16.
__device__ inline void gld_lds16(const unsigned short* g, unsigned short* l) {
    __builtin_amdgcn_global_load_lds(
        (const __attribute__((address_space(1))) unsigned int*)(const void*)g,
        (__attribute__((address_space(3))) unsigned int*)(void*)l,
        16, 0, 0);
}

// W[K=1024][N=1024] fp32 -> Wt bf16 in A/W swizzle (transpose+convert). z selects tensor.
__global__ __launch_bounds__(256)
void cvt3(const float* __restrict__ W0, const float* __restrict__ W1, const float* __restrict__ W2,
          unsigned short* __restrict__ T0, unsigned short* __restrict__ T1, unsigned short* __restrict__ T2) {
    const float* W = (blockIdx.z == 0) ? W0 : (blockIdx.z == 1) ? W1 : W2;
    unsigned short* Wt = (blockIdx.z == 0) ? T0 : (blockIdx.z == 1) ? T1 : T2;
    __shared__ __align__(16) unsigned short Ls[64 * 72];
    const int t = threadIdx.x;
    const int k0 = blockIdx.y * 64, n0 = blockIdx.x * 64;
    const int r = t >> 4, c4 = (t & 15) * 4;
    #pragma unroll
    for (int i = 0; i < 4; ++i) {
        float4 wv = *(const float4*)&W[(size_t)(k0 + r + i * 16) * 1024 + n0 + c4];
        Ls[(c4 + 0) * 72 + r + i * 16] = f2bf(wv.x);
        Ls[(c4 + 1) * 72 + r + i * 16] = f2bf(wv.y);
        Ls[(c4 + 2) * 72 + r + i * 16] = f2bf(wv.z);
        Ls[(c4 + 3) * 72 + r + i * 16] = f2bf(wv.w);
    }
    __syncthreads();
    #pragma unroll
    for (int i = 0; i < 2; ++i) {
        const int p = i * 256 + t;
        const int n = p & 63, kc = p >> 6;
        s16x8 v = *(const s16x8*)&Ls[n * 72 + kc * 8];
        const int gn = n0 + n, k = k0 + kc * 8;
        const size_t g = ((size_t)(gn >> 7) * 128 + (k >> 3)) * 128 + (gn & 127);
        *(s16x8*)&Wt[g * 8] = v;
    }
}

// Fused QKV GEMM: C = X @ W^T per z in {Q,K,V}. 128x128 tile, BK=64.
// A fp32 row-major (in-register explicit pack, XOR-swizzled LDS); B via DMA.
// Grid (8, 32, 3) = 768 blocks -> 3 blocks/CU.
__global__ __launch_bounds__(256, 3)
void gemm_qkv(const float* __restrict__ A0, const float* __restrict__ A1, const float* __restrict__ A2,
              const unsigned short* __restrict__ W0, const unsigned short* __restrict__ W1,
              const unsigned short* __restrict__ W2,
              unsigned short* __restrict__ OQ, unsigned short* __restrict__ OK,
              unsigned short* __restrict__ OV, float scaleQ) {
    const int z = blockIdx.z;
    const float* Av = (z == 0) ? A0 : (z == 1) ? A1 : A2;
    const unsigned short* Bsw = (z == 0) ? W0 : (z == 1) ? W1 : W2;
    const float scale = (z == 0) ? scaleQ : 1.0f;

    __shared__ __align__(16) unsigned short Al[1024 * 8];
    __shared__ __align__(16) unsigned short Bl[1024 * 8];
    const int t = threadIdx.x;
    const int lane = t & 63, w = t >> 6;
    const int ln = lane & 15, qd = lane >> 4;
    const int mw = (w & 1) * 64, nw = (w >> 1) * 64;
    const int m0 = blockIdx.y * 128, n0 = blockIdx.x * 128;

    f32x4v acc[4][4] = {};

    for (int k0 = 0; k0 < 1024; k0 += 64) {
        __syncthreads();
        {   // B: contiguous DMA (per-lane address via t)
            const size_t gb = ((size_t)(n0 >> 7) * 128 + (k0 >> 3)) * 128;
            #pragma unroll
            for (int j = 0; j < 4; ++j)
                gld_lds16(Bsw + (gb + j * 256 + t) * 8, &Bl[(j * 256 + w * 64) * 8]);
        }
        #pragma unroll
        for (int j = 0; j < 4; ++j) {       // A: fp32 -> bf16, explicit pack
            const int p = j * 256 + t;
            const int row = p >> 3, kc = p & 7;
            const float* src = Av + (size_t)(m0 + row) * 1024 + k0 + kc * 8;
            float4 f0 = ((const float4*)src)[0];
            float4 f1 = ((const float4*)src)[1];
            uint4 u;
            u.x = pkbf(f0.x, f0.y); u.y = pkbf(f0.z, f0.w);
            u.z = pkbf(f1.x, f1.y); u.w = pkbf(f1.z, f1.w);
            *(uint4*)&Al[(kc * 128 + (row ^ kc)) * 8] = u;
        }
        __syncthreads();

        #pragma unroll
        for (int kk = 0; kk < 2; ++kk) {
            const int kc = kk * 4 + qd;
            s16x8 a[4], b[4];
            #pragma unroll
            for (int mt = 0; mt < 4; ++mt)
                a[mt] = *(const s16x8*)&Al[(kc * 128 + ((mw + mt * 16 + ln) ^ kc)) * 8];
            #pragma unroll
            for (int nt = 0; nt < 4; ++nt)
                b[nt] = *(const s16x8*)&Bl[(kc * 128 + nw + nt * 16 + ln) * 8];
            #pragma unroll
            for (int mt = 0; mt < 4; ++mt)
                #pragma unroll
                for (int nt = 0; nt < 4; ++nt)
                    acc[mt][nt] = __builtin_amdgcn_mfma_f32_16x16x32_bf16(a[mt], b[nt], acc[mt][nt], 0, 0, 0);
        }
    }

    #pragma unroll
    for (int mt = 0; mt < 4; ++mt)
        #pragma unroll
        for (int nt = 0; nt < 4; ++nt)
            #pragma unroll
            for (int i = 0; i < 4; ++i) {
                const int m = m0 + mw + mt * 16 + qd * 4 + i;
                const int n = n0 + nw + nt * 16 + ln;
                const float v = acc[mt][nt][i] * scale;
                const int bh = (m >> 11) * 16 + (n >> 6), s = m & 2047, hd = n & 63;
                if (z == 0) {
                    OQ[((size_t)bh * 2048 + s) * 64 + hd] = f2bf(v);
                } else if (z == 1) {
                    const size_t g = ((size_t)(bh * 32 + (s >> 6)) * 8 + (hd >> 3)) * 64 + (s & 63);
                    OK[g * 8 + (hd & 7)] = f2bf(v);
                } else {
                    const size_t g = ((size_t)(bh * 32 + (s >> 6)) * 8 + ((s >> 3) & 7)) * 64 + hd;
                    OV[g * 8 + (s & 7)] = f2bf(v);
                }
            }
}

// Output GEMM: out[M=4096][N=1024] fp32 = ctx_sw @ Wot^T. 128x64 tile, BK=64.
// Grid (16, 32) = 512 blocks -> 2 blocks/CU. Wave tile 64x32.
__global__ __launch_bounds__(256, 2)
void gemm_out(const unsigned short* __restrict__ Asw, const unsigned short* __restrict__ Bsw,
              float* __restrict__ outF) {
    __shared__ __align__(16) unsigned short Al[1024 * 8];
    __shared__ __align__(16) unsigned short Bl[512 * 8];
    const int t = threadIdx.x;
    const int lane = t & 63, w = t >> 6;
    const int ln = lane & 15, qd = lane >> 4;
    const int mw = (w & 1) * 64, nw = (w >> 1) * 32;
    const int m0 = blockIdx.y * 128, n0 = blockIdx.x * 64;

    f32x4v acc[4][2] = {};

    for (int k0 = 0; k0 < 1024; k0 += 64) {
        __syncthreads();
        {   // A: 1024 contiguous blocks (per-lane address via t)
            const size_t ga = ((size_t)(m0 >> 7) * 128 + (k0 >> 3)) * 128;
            #pragma unroll
            for (int j = 0; j < 4; ++j)
                gld_lds16(Asw + (ga + j * 256 + t) * 8, &Al[(j * 256 + w * 64) * 8]);
        }
        {   // B: 8 chunks of 64 contiguous blocks; wave w takes chunks 2w, 2w+1.
            #pragma unroll
            for (int i = 0; i < 2; ++i) {
                const int c = w * 2 + i;
                const size_t gb = ((size_t)(n0 >> 7) * 128 + (k0 >> 3) + c) * 128 + (n0 & 127) + lane;
                gld_lds16(Bsw + gb * 8, &Bl[(c * 64) * 8]);
            }
        }
        __syncthreads();

        #pragma unroll
        for (int kk = 0; kk < 2; ++kk) {
            const int kc = kk * 4 + qd;
            s16x8 a[4], b[2];
            #pragma unroll
            for (int mt = 0; mt < 4; ++mt)
                a[mt] = *(const s16x8*)&Al[(kc * 128 + mw + mt * 16 + ln) * 8];
            #pragma unroll
            for (int nt = 0; nt < 2; ++nt)
                b[nt] = *(const s16x8*)&Bl[(kc * 64 + nw + nt * 16 + ln) * 8];
            #pragma unroll
            for (int mt = 0; mt < 4; ++mt)
                #pragma unroll
                for (int nt = 0; nt < 2; ++nt)
                    acc[mt][nt] = __builtin_amdgcn_mfma_f32_16x16x32_bf16(a[mt], b[nt], acc[mt][nt], 0, 0, 0);
        }
    }

    #pragma unroll
    for (int mt = 0; mt < 4; ++mt)
        #pragma unroll
        for (int nt = 0; nt < 2; ++nt)
            #pragma unroll
            for (int i = 0; i < 4; ++i) {
                const int m = m0 + mw + mt * 16 + qd * 4 + i;
                const int n = n0 + nw + nt * 16 + ln;
                outF[(size_t)m * 1024 + n] = acc[mt][nt][i];
            }
}

// Flash attention v4: LDS-free, barrier-free. 4 waves x 32q per block, 32x32x16 MFMA.
// Each wave loads its own K/V fragments straight to registers: in the K_sw/V_sw
// layouts a fragment is 32 lanes x 16B contiguous (per-lane coalesced dwordx4).
// K is double-buffered one tile ahead (kfA/kfB ping-pong, kt-loop unrolled by 2);
// V is issued at tile top and consumed ~at tile end. Waves free-run staggered so
// one wave's exp/pack overlaps another's MFMA; compiler emits counted vmcnt waits.
// Swapped QK^T: accS[mt] = mfma(A=Kfrag, B=Qfrag) -> S^T lane-resident:
//   lane (l31,H) reg r of accS[mt]: q = l31, k = mt*32 + (r&3)+8*(r>>2)+4*H.
// P=2^S packed via v_cvt_pk_bf16_f32; v_permlane32_swap_b32 assembles PV A-frags.
// Bijective XCD swizzle: 64-block chunks per XCD = 4 heads/XCD (K/V 2MB per 4MB L2).

__device__ __forceinline__ void fa_tile(
        const unsigned short* __restrict__ vt,   // V tile base (per-lane)
        const unsigned short* __restrict__ kn,   // next K tile base (per-lane)
        const s16x8* kcur, s16x8* knext, const s16x8* qf,
        f32x16v* accO, float& ls0, float& ls1, float& ls2, float& ls3) {
    s16x8 vf[8];
    #pragma unroll
    for (int u = 0; u < 8; ++u)
        vf[u] = *(const s16x8*)(vt + (u >> 1) * 1024 + (u & 1) * 256);
    #pragma unroll
    for (int u = 0; u < 8; ++u)
        knext[u] = *(const s16x8*)(kn + (u >> 1) * 1024 + (u & 1) * 256);

    f32x16v accS[2] = {};
    #pragma unroll
    for (int kk = 0; kk < 4; ++kk) {
        accS[0] = __builtin_amdgcn_mfma_f32_32x32x16_bf16(kcur[kk * 2 + 0], qf[kk], accS[0], 0, 0, 0);
        accS[1] = __builtin_amdgcn_mfma_f32_32x32x16_bf16(kcur[kk * 2 + 1], qf[kk], accS[1], 0, 0, 0);
    }

    u32x4v af[4];
    #pragma unroll
    for (int mt = 0; mt < 2; ++mt) {
        float p[16];
        #pragma unroll
        for (int r = 0; r < 16; ++r)
            p[r] = exp2f(accS[mt][r]);
        #pragma unroll
        for (int r = 0; r < 16; r += 4) {
            ls0 += p[r + 0]; ls1 += p[r + 1]; ls2 += p[r + 2]; ls3 += p[r + 3];
        }
        unsigned int C[8];
        #pragma unroll
        for (int j = 0; j < 8; ++j)
            asm("v_cvt_pk_bf16_f32 %0, %1, %2" : "=v"(C[j]) : "v"(p[2 * j]), "v"(p[2 * j + 1]));
        #pragma unroll
        for (int pp = 0; pp < 2; ++pp) {
            unsigned int x0 = C[4 * pp + 0], y0 = C[4 * pp + 2];
            unsigned int x1 = C[4 * pp + 1], y1 = C[4 * pp + 3];
            asm("v_permlane32_swap_b32 %0, %1" : "+v"(x0), "+v"(y0));
            asm("v_permlane32_swap_b32 %0, %1" : "+v"(x1), "+v"(y1));
            u32x4v a; a.x = x0; a.y = x1; a.z = y0; a.w = y1;
            af[mt * 2 + pp] = a;
        }
    }

    #pragma unroll
    for (int kk2 = 0; kk2 < 4; ++kk2) {
        s16x8 a = __builtin_bit_cast(s16x8, af[kk2]);
        accO[0] = __builtin_amdgcn_mfma_f32_32x32x16_bf16(a, vf[kk2 * 2 + 0], accO[0], 0, 0, 0);
        accO[1] = __builtin_amdgcn_mfma_f32_32x32x16_bf16(a, vf[kk2 * 2 + 1], accO[1], 0, 0, 0);
    }
}

__global__ __launch_bounds__(256, 2)
void fattn(const unsigned short* __restrict__ Q, const unsigned short* __restrict__ Ksw,
           const unsigned short* __restrict__ Vsw, unsigned short* __restrict__ ctx) {
    const int t = threadIdx.x, lane = t & 63, w = t >> 6;
    const int l31 = lane & 31, H = lane >> 5;
    // XCD swizzle (512 = 8 XCD x 64): chunk c gets heads 4c..4c+3, all 16 m-blocks.
    const int bid = blockIdx.x + (blockIdx.y << 4);
    const int wid = (bid & 7) * 64 + (bid >> 3);
    const int bh = wid >> 4, m0 = (wid & 15) * 128;
    const size_t head = (size_t)bh * 2048 * 64;

    // Q B-frag: lane holds Q[q=l31][d = kk*16 + H*8 + 0..7], q-rows m0 + w*32 + l31
    s16x8 qf[4];
    #pragma unroll
    for (int kk = 0; kk < 4; ++kk)
        qf[kk] = *(const s16x8*)(Q + head + (size_t)(m0 + w * 32 + l31) * 64 + kk * 16 + H * 8);

    // Per-lane fragment base: elem off = (kc*64 + row)*8; kc = (u>>1)*2 + H, row =
    // (u&1)*32 + l31. Lane part folded into base: H*512 + l31*8.
    const unsigned short* kb = Ksw + (size_t)bh * 32 * 4096 + H * 512 + l31 * 8;
    const unsigned short* vb = Vsw + (size_t)bh * 32 * 4096 + H * 512 + l31 * 8;

    f32x16v accO[2] = {};
    float ls0 = 0.f, ls1 = 0.f, ls2 = 0.f, ls3 = 0.f;

    s16x8 kfA[8], kfB[8];
    #pragma unroll
    for (int u = 0; u < 8; ++u)       // preload K tile 0
        kfA[u] = *(const s16x8*)(kb + (u >> 1) * 1024 + (u & 1) * 256);

    for (int kt2 = 0; kt2 < 16; ++kt2) {
        // (kt+1)&31 on the last tile wraps to tile 0: dead value, in-bounds.
        fa_tile(vb + (size_t)(2 * kt2) * 4096,
                kb + (size_t)((2 * kt2 + 1) & 31) * 4096,
                kfA, kfB, qf, accO, ls0, ls1, ls2, ls3);
        fa_tile(vb + (size_t)(2 * kt2 + 1) * 4096,
                kb + (size_t)((2 * kt2 + 2) & 31) * 4096,
                kfB, kfA, qf, accO, ls0, ls1, ls2, ls3);
    }

    // full row-sum for q=l31: other half holds the other 32 k's per tile
    float lsum = (ls0 + ls1) + (ls2 + ls3);
    lsum += __shfl_xor(lsum, 32, 64);
    const float inv = 1.f / lsum;

    // ctx in A/W swizzle: m = b*2048+s, k = h*64+d
    #pragma unroll
    for (int r = 0; r < 16; ++r) {
        const int qloc = (r & 3) + 8 * (r >> 2) + 4 * H;
        const float rinv = __shfl(inv, qloc, 64);   // lane qloc holds rowsum[q=qloc]
        const int mrow = (bh >> 4) * 2048 + m0 + w * 32 + qloc;
        #pragma unroll
        for (int nt = 0; nt < 2; ++nt) {
            const int k = (bh & 15) * 64 + nt * 32 + l31;
            const size_t g = ((size_t)(mrow >> 7) * 128 + (k >> 3)) * 128 + (mrow & 127);
            ctx[g * 8 + (k & 7)] = f2bf(accO[nt][r] * rinv);
        }
    }
}

extern "C" void kernel_launch(void* const* d_in, const int* in_sizes, int n_in,
                              void* d_out, int out_size, void* d_ws, size_t ws_size,
                              hipStream_t stream) {
    char* ws = (char*)d_ws;
    unsigned short* Qb  = (unsigned short*)(ws);
    unsigned short* Ksw = (unsigned short*)(ws + ((size_t)8 << 20));
    unsigned short* Vsw = (unsigned short*)(ws + ((size_t)16 << 20));
    unsigned short* Wqt = (unsigned short*)(ws + ((size_t)24 << 20));
    unsigned short* Wkt = (unsigned short*)(ws + ((size_t)26 << 20));
    unsigned short* Wvt = (unsigned short*)(ws + ((size_t)28 << 20));
    unsigned short* ctx = (unsigned short*)(ws + ((size_t)24 << 20));  // after QKV GEMM
    unsigned short* Wot = (unsigned short*)(ws);                        // after fattn (Qb dead)

    cvt3<<<dim3(16, 16, 3), 256, 0, stream>>>((const float*)d_in[3], (const float*)d_in[4],
                                              (const float*)d_in[5], Wqt, Wkt, Wvt);

    gemm_qkv<<<dim3(8, 32, 3), 256, 0, stream>>>(
        (const float*)d_in[0], (const float*)d_in[1], (const float*)d_in[2],
        Wqt, Wkt, Wvt, Qb, Ksw, Vsw, 0.125f * 1.44269504f);

    fattn<<<dim3(16, 32), dim3(256), 0, stream>>>(Qb, Ksw, Vsw, ctx);

    cvt3<<<dim3(16, 16, 1), 256, 0, stream>>>((const float*)d_in[6], nullptr, nullptr,
                                              Wot, nullptr, nullptr);

    gemm_out<<<dim3(16, 32), 256, 0, stream>>>(ctx, Wot, (float*)d_out);
}

// Round 5
// 241.278 us; speedup vs baseline: 1.1532x; 1.1532x over previous
//
#include <hip/hip_runtime.h>
#include <hip/hip_bf16.h>

// MHA: B=2, S=2048, D=1024, H=16, HD=64. fp32 in, fp32 out.
// Swizzled bf16 inter-kernel layouts (16B blocks) so all staging is contiguous DMA:
//   A/W swizzle ([R][K=1024]): block g=((r>>7)*128+(k>>3))*128+(r&127)
//   K_sw/V_sw: block g=((bh*32+kt)*8+kc)*64+row
// ws: [0,8)MB Qb [B,H,S,HD] | [8,16) K_sw | [16,24) V_sw | [24,32) Wqt/Wkt/Wvt (2MB each)
//     ctx_sw overlays [24,32) after QKV GEMM; Wot overlays [0,2) after fattn.
// Q-proj scale folds 1/sqrt(HD)*log2(e) so fattn uses native exp2.
// R9: 4 waves x 32q, 32x32x16, swapped QK^T, cvt_pk+permlane P-frags: 70us,
//     stall ~50% (vmcnt(0) drain at __syncthreads + FETCH 70MB = HBM-latency waits).
// R10: PV pipelining: null. Within-wave scheduling is not the constraint.
// R11/R12: LDS-free reg loads + XCD swizzle: FETCH 70->12MB (swizzle PROVEN) but
//     103us — per-tile reg-load latency at 2 waves/SIMD is worse than the DMA drain.
// R13 (this): R9 LDS-DMA structure + XCD swizzle + T4 counted vmcnt across raw
//     s_barrier: 3 LDS buffers, 2-tile lookahead, per-tile s_waitcnt vmcnt(4) (tile
//     kt+1 stays in flight across the barrier), last tile peeled with vmcnt(0).
//     Q-frags materialized pre-loop (vmcnt(0) + reg-passthrough asm) so the compiler
//     waitcnt pass has no load-use to drain inside the loop.

typedef short s16x8 __attribute__((ext_vector_type(8)));
typedef float f32x4v __attribute__((ext_vector_type(4)));
typedef float f32x16v __attribute__((ext_vector_type(16)));
typedef unsigned int u32x4v __attribute__((ext_vector_type(4)));

__device__ inline unsigned short f2bf(float f) {   // RNE (proven R2-R6)
    union { float f; unsigned int i; } x; x.f = f;
    unsigned int r = x.i + 0x7FFFu + ((x.i >> 16) & 1u);
    return (unsigned short)(r >> 16);
}
__device__ inline unsigned int pkbf(float lo, float hi) {  // lo16=bf(lo), hi16=bf(hi)
    return (unsigned int)f2bf(lo) | ((unsigned int)f2bf(hi) << 16);
}

// async global->LDS, 16B/lane. Global address PER-LANE; LDS base wave-uniform,
// HW writes base + lane*16.
__device__ inline void gld_lds16(const unsigned short* g, unsigned short* l) {
    __builtin_amdgcn_global_load_lds(
        (const __attribute__((address_space(1))) unsigned int*)(const void*)g,
        (__attribute__((address_space(3))) unsigned int*)(void*)l,
        16, 0, 0);
}

// W[K=1024][N=1024] fp32 -> Wt bf16 in A/W swizzle (transpose+convert). z selects tensor.
__global__ __launch_bounds__(256)
void cvt3(const float* __restrict__ W0, const float* __restrict__ W1, const float* __restrict__ W2,
          unsigned short* __restrict__ T0, unsigned short* __restrict__ T1, unsigned short* __restrict__ T2) {
    const float* W = (blockIdx.z == 0) ? W0 : (blockIdx.z == 1) ? W1 : W2;
    unsigned short* Wt = (blockIdx.z == 0) ? T0 : (blockIdx.z == 1) ? T1 : T2;
    __shared__ __align__(16) unsigned short Ls[64 * 72];
    const int t = threadIdx.x;
    const int k0 = blockIdx.y * 64, n0 = blockIdx.x * 64;
    const int r = t >> 4, c4 = (t & 15) * 4;
    #pragma unroll
    for (int i = 0; i < 4; ++i) {
        float4 wv = *(const float4*)&W[(size_t)(k0 + r + i * 16) * 1024 + n0 + c4];
        Ls[(c4 + 0) * 72 + r + i * 16] = f2bf(wv.x);
        Ls[(c4 + 1) * 72 + r + i * 16] = f2bf(wv.y);
        Ls[(c4 + 2) * 72 + r + i * 16] = f2bf(wv.z);
        Ls[(c4 + 3) * 72 + r + i * 16] = f2bf(wv.w);
    }
    __syncthreads();
    #pragma unroll
    for (int i = 0; i < 2; ++i) {
        const int p = i * 256 + t;
        const int n = p & 63, kc = p >> 6;
        s16x8 v = *(const s16x8*)&Ls[n * 72 + kc * 8];
        const int gn = n0 + n, k = k0 + kc * 8;
        const size_t g = ((size_t)(gn >> 7) * 128 + (k >> 3)) * 128 + (gn & 127);
        *(s16x8*)&Wt[g * 8] = v;
    }
}

// Fused QKV GEMM: C = X @ W^T per z in {Q,K,V}. 128x128 tile, BK=64.
// A fp32 row-major (in-register explicit pack, XOR-swizzled LDS); B via DMA.
// Grid (8, 32, 3) = 768 blocks -> 3 blocks/CU.
__global__ __launch_bounds__(256, 3)
void gemm_qkv(const float* __restrict__ A0, const float* __restrict__ A1, const float* __restrict__ A2,
              const unsigned short* __restrict__ W0, const unsigned short* __restrict__ W1,
              const unsigned short* __restrict__ W2,
              unsigned short* __restrict__ OQ, unsigned short* __restrict__ OK,
              unsigned short* __restrict__ OV, float scaleQ) {
    const int z = blockIdx.z;
    const float* Av = (z == 0) ? A0 : (z == 1) ? A1 : A2;
    const unsigned short* Bsw = (z == 0) ? W0 : (z == 1) ? W1 : W2;
    const float scale = (z == 0) ? scaleQ : 1.0f;

    __shared__ __align__(16) unsigned short Al[1024 * 8];
    __shared__ __align__(16) unsigned short Bl[1024 * 8];
    const int t = threadIdx.x;
    const int lane = t & 63, w = t >> 6;
    const int ln = lane & 15, qd = lane >> 4;
    const int mw = (w & 1) * 64, nw = (w >> 1) * 64;
    const int m0 = blockIdx.y * 128, n0 = blockIdx.x * 128;

    f32x4v acc[4][4] = {};

    for (int k0 = 0; k0 < 1024; k0 += 64) {
        __syncthreads();
        {   // B: contiguous DMA (per-lane address via t)
            const size_t gb = ((size_t)(n0 >> 7) * 128 + (k0 >> 3)) * 128;
            #pragma unroll
            for (int j = 0; j < 4; ++j)
                gld_lds16(Bsw + (gb + j * 256 + t) * 8, &Bl[(j * 256 + w * 64) * 8]);
        }
        #pragma unroll
        for (int j = 0; j < 4; ++j) {       // A: fp32 -> bf16, explicit pack
            const int p = j * 256 + t;
            const int row = p >> 3, kc = p & 7;
            const float* src = Av + (size_t)(m0 + row) * 1024 + k0 + kc * 8;
            float4 f0 = ((const float4*)src)[0];
            float4 f1 = ((const float4*)src)[1];
            uint4 u;
            u.x = pkbf(f0.x, f0.y); u.y = pkbf(f0.z, f0.w);
            u.z = pkbf(f1.x, f1.y); u.w = pkbf(f1.z, f1.w);
            *(uint4*)&Al[(kc * 128 + (row ^ kc)) * 8] = u;
        }
        __syncthreads();

        #pragma unroll
        for (int kk = 0; kk < 2; ++kk) {
            const int kc = kk * 4 + qd;
            s16x8 a[4], b[4];
            #pragma unroll
            for (int mt = 0; mt < 4; ++mt)
                a[mt] = *(const s16x8*)&Al[(kc * 128 + ((mw + mt * 16 + ln) ^ kc)) * 8];
            #pragma unroll
            for (int nt = 0; nt < 4; ++nt)
                b[nt] = *(const s16x8*)&Bl[(kc * 128 + nw + nt * 16 + ln) * 8];
            #pragma unroll
            for (int mt = 0; mt < 4; ++mt)
                #pragma unroll
                for (int nt = 0; nt < 4; ++nt)
                    acc[mt][nt] = __builtin_amdgcn_mfma_f32_16x16x32_bf16(a[mt], b[nt], acc[mt][nt], 0, 0, 0);
        }
    }

    #pragma unroll
    for (int mt = 0; mt < 4; ++mt)
        #pragma unroll
        for (int nt = 0; nt < 4; ++nt)
            #pragma unroll
            for (int i = 0; i < 4; ++i) {
                const int m = m0 + mw + mt * 16 + qd * 4 + i;
                const int n = n0 + nw + nt * 16 + ln;
                const float v = acc[mt][nt][i] * scale;
                const int bh = (m >> 11) * 16 + (n >> 6), s = m & 2047, hd = n & 63;
                if (z == 0) {
                    OQ[((size_t)bh * 2048 + s) * 64 + hd] = f2bf(v);
                } else if (z == 1) {
                    const size_t g = ((size_t)(bh * 32 + (s >> 6)) * 8 + (hd >> 3)) * 64 + (s & 63);
                    OK[g * 8 + (hd & 7)] = f2bf(v);
                } else {
                    const size_t g = ((size_t)(bh * 32 + (s >> 6)) * 8 + ((s >> 3) & 7)) * 64 + hd;
                    OV[g * 8 + (s & 7)] = f2bf(v);
                }
            }
}

// Output GEMM: out[M=4096][N=1024] fp32 = ctx_sw @ Wot^T. 128x64 tile, BK=64.
// Grid (16, 32) = 512 blocks -> 2 blocks/CU. Wave tile 64x32.
__global__ __launch_bounds__(256, 2)
void gemm_out(const unsigned short* __restrict__ Asw, const unsigned short* __restrict__ Bsw,
              float* __restrict__ outF) {
    __shared__ __align__(16) unsigned short Al[1024 * 8];
    __shared__ __align__(16) unsigned short Bl[512 * 8];
    const int t = threadIdx.x;
    const int lane = t & 63, w = t >> 6;
    const int ln = lane & 15, qd = lane >> 4;
    const int mw = (w & 1) * 64, nw = (w >> 1) * 32;
    const int m0 = blockIdx.y * 128, n0 = blockIdx.x * 64;

    f32x4v acc[4][2] = {};

    for (int k0 = 0; k0 < 1024; k0 += 64) {
        __syncthreads();
        {   // A: 1024 contiguous blocks (per-lane address via t)
            const size_t ga = ((size_t)(m0 >> 7) * 128 + (k0 >> 3)) * 128;
            #pragma unroll
            for (int j = 0; j < 4; ++j)
                gld_lds16(Asw + (ga + j * 256 + t) * 8, &Al[(j * 256 + w * 64) * 8]);
        }
        {   // B: 8 chunks of 64 contiguous blocks; wave w takes chunks 2w, 2w+1.
            #pragma unroll
            for (int i = 0; i < 2; ++i) {
                const int c = w * 2 + i;
                const size_t gb = ((size_t)(n0 >> 7) * 128 + (k0 >> 3) + c) * 128 + (n0 & 127) + lane;
                gld_lds16(Bsw + gb * 8, &Bl[(c * 64) * 8]);
            }
        }
        __syncthreads();

        #pragma unroll
        for (int kk = 0; kk < 2; ++kk) {
            const int kc = kk * 4 + qd;
            s16x8 a[4], b[2];
            #pragma unroll
            for (int mt = 0; mt < 4; ++mt)
                a[mt] = *(const s16x8*)&Al[(kc * 128 + mw + mt * 16 + ln) * 8];
            #pragma unroll
            for (int nt = 0; nt < 2; ++nt)
                b[nt] = *(const s16x8*)&Bl[(kc * 64 + nw + nt * 16 + ln) * 8];
            #pragma unroll
            for (int mt = 0; mt < 4; ++mt)
                #pragma unroll
                for (int nt = 0; nt < 2; ++nt)
                    acc[mt][nt] = __builtin_amdgcn_mfma_f32_16x16x32_bf16(a[mt], b[nt], acc[mt][nt], 0, 0, 0);
        }
    }

    #pragma unroll
    for (int mt = 0; mt < 4; ++mt)
        #pragma unroll
        for (int nt = 0; nt < 2; ++nt)
            #pragma unroll
            for (int i = 0; i < 4; ++i) {
                const int m = m0 + mw + mt * 16 + qd * 4 + i;
                const int n = n0 + nw + nt * 16 + ln;
                outF[(size_t)m * 1024 + n] = acc[mt][nt][i];
            }
}

// Flash attention v5: 4 waves x 32q, 32x32x16 MFMA, 3-buffer LDS DMA with 2-tile
// lookahead, counted vmcnt across RAW s_barrier (one barrier per tile, never
// vmcnt(0) in the main loop). Grid (16,32), 256 thr, XCD-swizzled block ids.
// Swapped QK^T: accS[mt] = mfma(A=Kfrag, B=Qfrag) -> S^T lane-resident:
//   lane (l31,H) reg r of accS[mt]: q = l31, k = mt*32 + (r&3)+8*(r>>2)+4*H.
// P=2^S via exp2; packed by v_cvt_pk_bf16_f32; v_permlane32_swap_b32 assembles the
// PV A-frags in-register. Safety: every ds_read result is consumed by an MFMA
// before the barrier (implicit lgkm waits), so buffer b may be re-DMA'd right
// after the barrier that ends tile b's consumers.

__device__ __forceinline__ void fa_compute(
        const unsigned short* Ksb, const unsigned short* Vsb,  // LDS tile bases
        const int H, const int l31, const s16x8* qf,
        f32x16v* accO, float& ls0, float& ls1, float& ls2, float& ls3) {
    // S^T = K Q^T (pre-scaled by log2e): A = K rows (64 keys = 2 blocks of 32)
    f32x16v accS[2] = {};
    #pragma unroll
    for (int kk = 0; kk < 4; ++kk) {
        s16x8 kf0 = *(const s16x8*)&Ksb[((kk * 2 + H) * 64 + l31) * 8];
        s16x8 kf1 = *(const s16x8*)&Ksb[((kk * 2 + H) * 64 + 32 + l31) * 8];
        accS[0] = __builtin_amdgcn_mfma_f32_32x32x16_bf16(kf0, qf[kk], accS[0], 0, 0, 0);
        accS[1] = __builtin_amdgcn_mfma_f32_32x32x16_bf16(kf1, qf[kk], accS[1], 0, 0, 0);
    }

    // P = 2^S, 4-way partial row-sums, pack to bf16, permlane-assemble A-frags
    u32x4v af[4];
    #pragma unroll
    for (int mt = 0; mt < 2; ++mt) {
        float p[16];
        #pragma unroll
        for (int r = 0; r < 16; ++r)
            p[r] = exp2f(accS[mt][r]);
        #pragma unroll
        for (int r = 0; r < 16; r += 4) {
            ls0 += p[r + 0]; ls1 += p[r + 1]; ls2 += p[r + 2]; ls3 += p[r + 3];
        }
        unsigned int C[8];
        #pragma unroll
        for (int j = 0; j < 8; ++j)
            asm("v_cvt_pk_bf16_f32 %0, %1, %2" : "=v"(C[j]) : "v"(p[2 * j]), "v"(p[2 * j + 1]));
        #pragma unroll
        for (int pp = 0; pp < 2; ++pp) {
            unsigned int x0 = C[4 * pp + 0], y0 = C[4 * pp + 2];
            unsigned int x1 = C[4 * pp + 1], y1 = C[4 * pp + 3];
            asm("v_permlane32_swap_b32 %0, %1" : "+v"(x0), "+v"(y0));
            asm("v_permlane32_swap_b32 %0, %1" : "+v"(x1), "+v"(y1));
            u32x4v a; a.x = x0; a.y = x1; a.z = y0; a.w = y1;
            af[mt * 2 + pp] = a;
        }
    }

    // O += P V : A = P rows (q), B = V^T rows (d)
    #pragma unroll
    for (int kk2 = 0; kk2 < 4; ++kk2) {
        s16x8 a = __builtin_bit_cast(s16x8, af[kk2]);
        s16x8 vf0 = *(const s16x8*)&Vsb[((kk2 * 2 + H) * 64 + l31) * 8];
        s16x8 vf1 = *(const s16x8*)&Vsb[((kk2 * 2 + H) * 64 + 32 + l31) * 8];
        accO[0] = __builtin_amdgcn_mfma_f32_32x32x16_bf16(a, vf0, accO[0], 0, 0, 0);
        accO[1] = __builtin_amdgcn_mfma_f32_32x32x16_bf16(a, vf1, accO[1], 0, 0, 0);
    }
}

__global__ __launch_bounds__(256, 2)
void fattn(const unsigned short* __restrict__ Q, const unsigned short* __restrict__ Ksw,
           const unsigned short* __restrict__ Vsw, unsigned short* __restrict__ ctx) {
    __shared__ __align__(16) unsigned short Ks3[3][512 * 8];
    __shared__ __align__(16) unsigned short Vs3[3][512 * 8];

    const int t = threadIdx.x, lane = t & 63, w = t >> 6;
    const int l31 = lane & 31, H = lane >> 5;
    // XCD swizzle (512 = 8 XCD x 64): chunk c gets heads 4c..4c+3, all 16 m-blocks.
    const int bid = blockIdx.x + (blockIdx.y << 4);
    const int wid = (bid & 7) * 64 + (bid >> 3);
    const int bh = wid >> 4, m0 = (wid & 15) * 128;
    const size_t head = (size_t)bh * 2048 * 64;

    // Q B-frag: lane holds Q[q=l31][d = kk*16 + H*8 + 0..7], q-rows m0 + w*32 + l31
    s16x8 qf[4];
    #pragma unroll
    for (int kk = 0; kk < 4; ++kk)
        qf[kk] = *(const s16x8*)(Q + head + (size_t)(m0 + w * 32 + l31) * 64 + kk * 16 + H * 8);
    // Materialize Q before any DMA: drain, then break the load->use chain so the
    // compiler's waitcnt pass never inserts its own drain inside the loop.
    asm volatile("s_waitcnt vmcnt(0)" ::: "memory");
    #pragma unroll
    for (int kk = 0; kk < 4; ++kk) {
        u32x4v q = __builtin_bit_cast(u32x4v, qf[kk]);
        asm volatile("" : "+v"(q.x), "+v"(q.y), "+v"(q.z), "+v"(q.w));
        qf[kk] = __builtin_bit_cast(s16x8, q);
    }

    const size_t tb = (size_t)bh * 32 * 512;
    {   // prologue: issue tiles 0,1 into buffers 0,1 (4 loads per tile per wave)
        #pragma unroll
        for (int kt = 0; kt < 2; ++kt)
            #pragma unroll
            for (int j = 0; j < 2; ++j) {
                gld_lds16(Ksw + (tb + kt * 512 + j * 256 + t) * 8, &Ks3[kt][(j * 256 + w * 64) * 8]);
                gld_lds16(Vsw + (tb + kt * 512 + j * 256 + t) * 8, &Vs3[kt][(j * 256 + w * 64) * 8]);
            }
    }

    f32x16v accO[2] = {};
    float ls0 = 0.f, ls1 = 0.f, ls2 = 0.f, ls3 = 0.f;

    int cur = 0;
    for (int kt = 0; kt < 31; ++kt) {
        // tile kt's 4 loads complete; tile kt+1's 4 stay in flight across the barrier
        asm volatile("s_waitcnt vmcnt(4)" ::: "memory");
        __builtin_amdgcn_s_barrier();
        asm volatile("" ::: "memory");
        if (kt < 30) {   // issue tile kt+2 into buffer (kt+2)%3 (freed by this barrier)
            const int ib = (cur == 0) ? 2 : cur - 1;
            const size_t tbn = tb + (size_t)(kt + 2) * 512;
            #pragma unroll
            for (int j = 0; j < 2; ++j) {
                gld_lds16(Ksw + (tbn + j * 256 + t) * 8, &Ks3[ib][(j * 256 + w * 64) * 8]);
                gld_lds16(Vsw + (tbn + j * 256 + t) * 8, &Vs3[ib][(j * 256 + w * 64) * 8]);
            }
        }
        fa_compute(Ks3[cur], Vs3[cur], H, l31, qf, accO, ls0, ls1, ls2, ls3);
        cur = (cur == 2) ? 0 : cur + 1;
    }
    // peeled last tile (kt=31, cur=1): drain is correct here, loop is done
    asm volatile("s_waitcnt vmcnt(0)" ::: "memory");
    __builtin_amdgcn_s_barrier();
    asm volatile("" ::: "memory");
    fa_compute(Ks3[cur], Vs3[cur], H, l31, qf, accO, ls0, ls1, ls2, ls3);

    // full row-sum for q=l31: other half holds the other 32 k's per tile
    float lsum = (ls0 + ls1) + (ls2 + ls3);
    lsum += __shfl_xor(lsum, 32, 64);
    const float inv = 1.f / lsum;

    // ctx in A/W swizzle: m = b*2048+s, k = h*64+d
    #pragma unroll
    for (int r = 0; r < 16; ++r) {
        const int qloc = (r & 3) + 8 * (r >> 2) + 4 * H;
        const float rinv = __shfl(inv, qloc, 64);   // lane qloc holds rowsum[q=qloc]
        const int mrow = (bh >> 4) * 2048 + m0 + w * 32 + qloc;
        #pragma unroll
        for (int nt = 0; nt < 2; ++nt) {
            const int k = (bh & 15) * 64 + nt * 32 + l31;
            const size_t g = ((size_t)(mrow >> 7) * 128 + (k >> 3)) * 128 + (mrow & 127);
            ctx[g * 8 + (k & 7)] = f2bf(accO[nt][r] * rinv);
        }
    }
}

extern "C" void kernel_launch(void* const* d_in, const int* in_sizes, int n_in,
                              void* d_out, int out_size, void* d_ws, size_t ws_size,
                              hipStream_t stream) {
    char* ws = (char*)d_ws;
    unsigned short* Qb  = (unsigned short*)(ws);
    unsigned short* Ksw = (unsigned short*)(ws + ((size_t)8 << 20));
    unsigned short* Vsw = (unsigned short*)(ws + ((size_t)16 << 20));
    unsigned short* Wqt = (unsigned short*)(ws + ((size_t)24 << 20));
    unsigned short* Wkt = (unsigned short*)(ws + ((size_t)26 << 20));
    unsigned short* Wvt = (unsigned short*)(ws + ((size_t)28 << 20));
    unsigned short* ctx = (unsigned short*)(ws + ((size_t)24 << 20));  // after QKV GEMM
    unsigned short* Wot = (unsigned short*)(ws);                        // after fattn (Qb dead)

    cvt3<<<dim3(16, 16, 3), 256, 0, stream>>>((const float*)d_in[3], (const float*)d_in[4],
                                              (const float*)d_in[5], Wqt, Wkt, Wvt);

    gemm_qkv<<<dim3(8, 32, 3), 256, 0, stream>>>(
        (const float*)d_in[0], (const float*)d_in[1], (const float*)d_in[2],
        Wqt, Wkt, Wvt, Qb, Ksw, Vsw, 0.125f * 1.44269504f);

    fattn<<<dim3(16, 32), dim3(256), 0, stream>>>(Qb, Ksw, Vsw, ctx);

    cvt3<<<dim3(16, 16, 1), 256, 0, stream>>>((const float*)d_in[6], nullptr, nullptr,
                                              Wot, nullptr, nullptr);

    gemm_out<<<dim3(16, 32), 256, 0, stream>>>(ctx, Wot, (float*)d_out);
}

// Round 6
// 233.025 us; speedup vs baseline: 1.1940x; 1.0354x over previous
//
#include <hip/hip_runtime.h>
#include <hip/hip_bf16.h>

// MHA: B=2, S=2048, D=1024, H=16, HD=64. fp32 in, fp32 out.
// Swizzled bf16 inter-kernel layouts (16B blocks) so all staging is contiguous DMA:
//   A/W swizzle ([R][K=1024]): block g=((r>>7)*128+(k>>3))*128+(r&127)
//   K_sw/V_sw: block g=((bh*32+kt)*8+kc)*64+row
// ws (big path, needs 54MB): [0,8)MB Qb | [8,16) Ksw | [16,24) Vsw | [24,30) Wq/k/vt
//   | [30,38) Aq | [38,46) Ak | [46,54) Av.  ctx overlays [24,32) after QKV GEMM
//   (W's and Aq dead); Wot overlays [0,2) after fattn (Qb dead).
// Q-proj scale folds 1/sqrt(HD)*log2(e) so fattn uses native exp2.
// R9:  fattn swapped-QK^T/permlane structure: 70us, latency-bound.
// R10: PV pipelining: null (barrier-locked phases).
// R11/R12: LDS-free fattn + XCD swizzle: FETCH 70->12MB (swizzle PROVEN) but 103us.
// R13: fattn 3-buf counted-vmcnt across raw s_barrier: modest gain (~65-70us).
// R14 (this): GEMMs. gemm_qkv was top kernel: FETCH 200MB (A panels re-fetched by 8
//   n-blocks on 8 XCDs), MfmaUtil 13%, in-loop fp32 pack on critical path, 1.5-round
//   tail (768 blocks @ 2/CU). Fix: cvtA pre-converts A to bf16 A/W-swizzle; gemm_qkv
//   rewritten both-operands-DMA, BK=32, 32KB LDS -> 3 blocks/CU (exactly 1 round),
//   XCD chunking (96 blocks/XCD), 2-buffer counted vmcnt(4). gemm_out same treatment
//   (vmcnt(6), 48KB, 2/CU, 1 round, chunk 64). Old pack-GEMM kept as ws<54MB fallback.

typedef short s16x8 __attribute__((ext_vector_type(8)));
typedef float f32x4v __attribute__((ext_vector_type(4)));
typedef float f32x16v __attribute__((ext_vector_type(16)));
typedef unsigned int u32x4v __attribute__((ext_vector_type(4)));

__device__ inline unsigned short f2bf(float f) {   // RNE (proven R2-R6)
    union { float f; unsigned int i; } x; x.f = f;
    unsigned int r = x.i + 0x7FFFu + ((x.i >> 16) & 1u);
    return (unsigned short)(r >> 16);
}
__device__ inline unsigned int pkbf(float lo, float hi) {  // lo16=bf(lo), hi16=bf(hi)
    return (unsigned int)f2bf(lo) | ((unsigned int)f2bf(hi) << 16);
}

// async global->LDS, 16B/lane. Global address PER-LANE; LDS base wave-uniform,
// HW writes base + lane*16.
__device__ inline void gld_lds16(const unsigned short* g, unsigned short* l) {
    __builtin_amdgcn_global_load_lds(
        (const __attribute__((address_space(1))) unsigned int*)(const void*)g,
        (__attribute__((address_space(3))) unsigned int*)(void*)l,
        16, 0, 0);
}

// W[K=1024][N=1024] fp32 -> Wt bf16 in A/W swizzle (transpose+convert). z selects tensor.
__global__ __launch_bounds__(256)
void cvt3(const float* __restrict__ W0, const float* __restrict__ W1, const float* __restrict__ W2,
          unsigned short* __restrict__ T0, unsigned short* __restrict__ T1, unsigned short* __restrict__ T2) {
    const float* W = (blockIdx.z == 0) ? W0 : (blockIdx.z == 1) ? W1 : W2;
    unsigned short* Wt = (blockIdx.z == 0) ? T0 : (blockIdx.z == 1) ? T1 : T2;
    __shared__ __align__(16) unsigned short Ls[64 * 72];
    const int t = threadIdx.x;
    const int k0 = blockIdx.y * 64, n0 = blockIdx.x * 64;
    const int r = t >> 4, c4 = (t & 15) * 4;
    #pragma unroll
    for (int i = 0; i < 4; ++i) {
        float4 wv = *(const float4*)&W[(size_t)(k0 + r + i * 16) * 1024 + n0 + c4];
        Ls[(c4 + 0) * 72 + r + i * 16] = f2bf(wv.x);
        Ls[(c4 + 1) * 72 + r + i * 16] = f2bf(wv.y);
        Ls[(c4 + 2) * 72 + r + i * 16] = f2bf(wv.z);
        Ls[(c4 + 3) * 72 + r + i * 16] = f2bf(wv.w);
    }
    __syncthreads();
    #pragma unroll
    for (int i = 0; i < 2; ++i) {
        const int p = i * 256 + t;
        const int n = p & 63, kc = p >> 6;
        s16x8 v = *(const s16x8*)&Ls[n * 72 + kc * 8];
        const int gn = n0 + n, k = k0 + kc * 8;
        const size_t g = ((size_t)(gn >> 7) * 128 + (k >> 3)) * 128 + (gn & 127);
        *(s16x8*)&Wt[g * 8] = v;
    }
}

// A[4096][1024] fp32 -> bf16 A/W swizzle (no transpose). Grid (16 k-tiles, 32 rp, 3 z).
// Tile 128 rows x 64 k. Output chunk = 1024 contiguous 16B blocks; LDS reorders.
__global__ __launch_bounds__(256)
void cvtA(const float* __restrict__ A0, const float* __restrict__ A1, const float* __restrict__ A2,
          unsigned short* __restrict__ O0, unsigned short* __restrict__ O1, unsigned short* __restrict__ O2) {
    const float* A = (blockIdx.z == 0) ? A0 : (blockIdx.z == 1) ? A1 : A2;
    unsigned short* O = (blockIdx.z == 0) ? O0 : (blockIdx.z == 1) ? O1 : O2;
    __shared__ __align__(16) unsigned short Ls[8192];   // 16 KB
    const int t = threadIdx.x;
    const int k0 = blockIdx.x * 64, rp = blockIdx.y;
    const int row = t >> 1, kh = (t & 1) * 32;
    const float* src = A + (size_t)(rp * 128 + row) * 1024 + k0 + kh;
    float4 f[8];
    #pragma unroll
    for (int i = 0; i < 8; ++i) f[i] = ((const float4*)src)[i];
    #pragma unroll
    for (int j = 0; j < 4; ++j) {
        uint4 u;
        u.x = pkbf(f[j * 2].x, f[j * 2].y);
        u.y = pkbf(f[j * 2].z, f[j * 2].w);
        u.z = pkbf(f[j * 2 + 1].x, f[j * 2 + 1].y);
        u.w = pkbf(f[j * 2 + 1].z, f[j * 2 + 1].w);
        const int kc = (t & 1) * 4 + j;
        *(uint4*)&Ls[(kc * 128 + row) * 8] = u;
    }
    __syncthreads();
    const size_t gbase = ((size_t)rp * 128 + (k0 >> 3)) * 128;
    #pragma unroll
    for (int i = 0; i < 4; ++i) {
        const int idx = i * 256 + t;
        *(uint4*)&O[(gbase + idx) * 8] = *(const uint4*)&Ls[idx * 8];
    }
}

// QKV GEMM (big-ws path): C = A_bf16 @ W^T, both operands DMA. 128x128 tile, BK=32.
// 32KB LDS -> 3 blocks/CU; grid 768 = exactly one round. 2-buffer counted vmcnt(4),
// raw s_barrier (never vmcnt(0) in-loop). XCD chunk: 96 blocks (12 m-panels x 8 n)
// per XCD -> each A panel fetched ~once into one L2.
__global__ __launch_bounds__(256, 3)
void gemm_qkv(const unsigned short* __restrict__ Aq, const unsigned short* __restrict__ Ak,
              const unsigned short* __restrict__ Av,
              const unsigned short* __restrict__ W0, const unsigned short* __restrict__ W1,
              const unsigned short* __restrict__ W2,
              unsigned short* __restrict__ OQ, unsigned short* __restrict__ OK,
              unsigned short* __restrict__ OV, float scaleQ) {
    const int p = blockIdx.x;
    const int L = (p & 7) * 96 + (p >> 3);          // 768 = 8 XCD x 96
    const int z = L >> 8;
    const int rem = L & 255;
    const int m0 = (rem >> 3) * 128, n0 = (rem & 7) * 128;
    const unsigned short* Asw = (z == 0) ? Aq : (z == 1) ? Ak : Av;
    const unsigned short* Bsw = (z == 0) ? W0 : (z == 1) ? W1 : W2;
    const float scale = (z == 0) ? scaleQ : 1.0f;

    __shared__ __align__(16) unsigned short Al[2][4096];   // 8 KB per buf
    __shared__ __align__(16) unsigned short Bl[2][4096];
    const int t = threadIdx.x, lane = t & 63, w = t >> 6;
    const int ln = lane & 15, qd = lane >> 4;
    const int mw = (w & 1) * 64, nw = (w >> 1) * 64;
    const size_t gaB = (size_t)(m0 >> 7) * 16384;
    const size_t gbB = (size_t)(n0 >> 7) * 16384;

    f32x4v acc[4][4] = {};

    auto stage = [&](int kt, int b) {   // 2 A + 2 B gld_lds16 per thread = 4 vm/wave
        const size_t ga = gaB + (size_t)kt * 512;
        const size_t gb = gbB + (size_t)kt * 512;
        #pragma unroll
        for (int j = 0; j < 2; ++j)
            gld_lds16(Asw + (ga + j * 256 + t) * 8, &Al[b][(j * 256 + w * 64) * 8]);
        #pragma unroll
        for (int j = 0; j < 2; ++j)
            gld_lds16(Bsw + (gb + j * 256 + t) * 8, &Bl[b][(j * 256 + w * 64) * 8]);
    };

    stage(0, 0);
    stage(1, 1);
    for (int kt = 0; kt < 32; ++kt) {
        if (kt < 31) asm volatile("s_waitcnt vmcnt(4)" ::: "memory");
        else         asm volatile("s_waitcnt vmcnt(0)" ::: "memory");
        __builtin_amdgcn_s_barrier();
        asm volatile("" ::: "memory");
        const int b = kt & 1;
        {
            s16x8 a[4], bb[4];
            #pragma unroll
            for (int mt = 0; mt < 4; ++mt)
                a[mt] = *(const s16x8*)&Al[b][(qd * 128 + mw + mt * 16 + ln) * 8];
            #pragma unroll
            for (int nt = 0; nt < 4; ++nt)
                bb[nt] = *(const s16x8*)&Bl[b][(qd * 128 + nw + nt * 16 + ln) * 8];
            #pragma unroll
            for (int mt = 0; mt < 4; ++mt)
                #pragma unroll
                for (int nt = 0; nt < 4; ++nt)
                    acc[mt][nt] = __builtin_amdgcn_mfma_f32_16x16x32_bf16(a[mt], bb[nt], acc[mt][nt], 0, 0, 0);
        }
        if (kt < 30) {
            __builtin_amdgcn_s_barrier();      // all waves done reading buf b
            asm volatile("" ::: "memory");
            stage(kt + 2, b);
        }
    }

    #pragma unroll
    for (int mt = 0; mt < 4; ++mt)
        #pragma unroll
        for (int nt = 0; nt < 4; ++nt)
            #pragma unroll
            for (int i = 0; i < 4; ++i) {
                const int m = m0 + mw + mt * 16 + qd * 4 + i;
                const int n = n0 + nw + nt * 16 + ln;
                const float v = acc[mt][nt][i] * scale;
                const int bh = (m >> 11) * 16 + (n >> 6), s = m & 2047, hd = n & 63;
                if (z == 0) {
                    OQ[((size_t)bh * 2048 + s) * 64 + hd] = f2bf(v);
                } else if (z == 1) {
                    const size_t g = ((size_t)(bh * 32 + (s >> 6)) * 8 + (hd >> 3)) * 64 + (s & 63);
                    OK[g * 8 + (hd & 7)] = f2bf(v);
                } else {
                    const size_t g = ((size_t)(bh * 32 + (s >> 6)) * 8 + ((s >> 3) & 7)) * 64 + hd;
                    OV[g * 8 + (s & 7)] = f2bf(v);
                }
            }
}

// Fallback QKV GEMM (ws < 54MB): original R0 kernel, fp32 A in-register pack.
__global__ __launch_bounds__(256, 3)
void gemm_qkv_pack(const float* __restrict__ A0, const float* __restrict__ A1, const float* __restrict__ A2,
                   const unsigned short* __restrict__ W0, const unsigned short* __restrict__ W1,
                   const unsigned short* __restrict__ W2,
                   unsigned short* __restrict__ OQ, unsigned short* __restrict__ OK,
                   unsigned short* __restrict__ OV, float scaleQ) {
    const int z = blockIdx.z;
    const float* Avv = (z == 0) ? A0 : (z == 1) ? A1 : A2;
    const unsigned short* Bsw = (z == 0) ? W0 : (z == 1) ? W1 : W2;
    const float scale = (z == 0) ? scaleQ : 1.0f;

    __shared__ __align__(16) unsigned short Al[1024 * 8];
    __shared__ __align__(16) unsigned short Bl[1024 * 8];
    const int t = threadIdx.x;
    const int lane = t & 63, w = t >> 6;
    const int ln = lane & 15, qd = lane >> 4;
    const int mw = (w & 1) * 64, nw = (w >> 1) * 64;
    const int m0 = blockIdx.y * 128, n0 = blockIdx.x * 128;

    f32x4v acc[4][4] = {};

    for (int k0 = 0; k0 < 1024; k0 += 64) {
        __syncthreads();
        {
            const size_t gb = ((size_t)(n0 >> 7) * 128 + (k0 >> 3)) * 128;
            #pragma unroll
            for (int j = 0; j < 4; ++j)
                gld_lds16(Bsw + (gb + j * 256 + t) * 8, &Bl[(j * 256 + w * 64) * 8]);
        }
        #pragma unroll
        for (int j = 0; j < 4; ++j) {
            const int pp = j * 256 + t;
            const int row = pp >> 3, kc = pp & 7;
            const float* src = Avv + (size_t)(m0 + row) * 1024 + k0 + kc * 8;
            float4 f0 = ((const float4*)src)[0];
            float4 f1 = ((const float4*)src)[1];
            uint4 u;
            u.x = pkbf(f0.x, f0.y); u.y = pkbf(f0.z, f0.w);
            u.z = pkbf(f1.x, f1.y); u.w = pkbf(f1.z, f1.w);
            *(uint4*)&Al[(kc * 128 + (row ^ kc)) * 8] = u;
        }
        __syncthreads();

        #pragma unroll
        for (int kk = 0; kk < 2; ++kk) {
            const int kc = kk * 4 + qd;
            s16x8 a[4], b[4];
            #pragma unroll
            for (int mt = 0; mt < 4; ++mt)
                a[mt] = *(const s16x8*)&Al[(kc * 128 + ((mw + mt * 16 + ln) ^ kc)) * 8];
            #pragma unroll
            for (int nt = 0; nt < 4; ++nt)
                b[nt] = *(const s16x8*)&Bl[(kc * 128 + nw + nt * 16 + ln) * 8];
            #pragma unroll
            for (int mt = 0; mt < 4; ++mt)
                #pragma unroll
                for (int nt = 0; nt < 4; ++nt)
                    acc[mt][nt] = __builtin_amdgcn_mfma_f32_16x16x32_bf16(a[mt], b[nt], acc[mt][nt], 0, 0, 0);
        }
    }

    #pragma unroll
    for (int mt = 0; mt < 4; ++mt)
        #pragma unroll
        for (int nt = 0; nt < 4; ++nt)
            #pragma unroll
            for (int i = 0; i < 4; ++i) {
                const int m = m0 + mw + mt * 16 + qd * 4 + i;
                const int n = n0 + nw + nt * 16 + ln;
                const float v = acc[mt][nt][i] * scale;
                const int bh = (m >> 11) * 16 + (n >> 6), s = m & 2047, hd = n & 63;
                if (z == 0) {
                    OQ[((size_t)bh * 2048 + s) * 64 + hd] = f2bf(v);
                } else if (z == 1) {
                    const size_t g = ((size_t)(bh * 32 + (s >> 6)) * 8 + (hd >> 3)) * 64 + (s & 63);
                    OK[g * 8 + (hd & 7)] = f2bf(v);
                } else {
                    const size_t g = ((size_t)(bh * 32 + (s >> 6)) * 8 + ((s >> 3) & 7)) * 64 + hd;
                    OV[g * 8 + (s & 7)] = f2bf(v);
                }
            }
}

// Output GEMM: out = ctx_sw @ Wot^T. 128x64 tile, BK=64, 2-buffer counted vmcnt(6),
// raw s_barrier. 48KB LDS @ 2 blocks/CU; grid 512 = one round. XCD chunk 64
// (4 m-panels x 16 n) -> A panel + 2MB Wot fit one L2.
__global__ __launch_bounds__(256, 2)
void gemm_out(const unsigned short* __restrict__ Asw, const unsigned short* __restrict__ Bsw,
              float* __restrict__ outF) {
    const int p = blockIdx.x;
    const int L = (p & 7) * 64 + (p >> 3);          // 512 = 8 XCD x 64
    const int m0 = (L >> 4) * 128, n0 = (L & 15) * 64;

    __shared__ __align__(16) unsigned short Al[2][8192];   // 16 KB per buf
    __shared__ __align__(16) unsigned short Bl[2][4096];   // 8 KB per buf
    const int t = threadIdx.x, lane = t & 63, w = t >> 6;
    const int ln = lane & 15, qd = lane >> 4;
    const int mw = (w & 1) * 64, nw = (w >> 1) * 32;
    const size_t gaB = (size_t)(m0 >> 7) * 16384;
    const size_t gbB = (size_t)(n0 >> 7) * 16384 + (n0 & 127);

    f32x4v acc[4][2] = {};

    auto stage = [&](int kt, int b) {   // 4 A + 2 B gld_lds16 per wave = 6 vm/wave
        const size_t ga = gaB + (size_t)kt * 1024;
        #pragma unroll
        for (int j = 0; j < 4; ++j)
            gld_lds16(Asw + (ga + j * 256 + t) * 8, &Al[b][(j * 256 + w * 64) * 8]);
        #pragma unroll
        for (int i = 0; i < 2; ++i) {
            const int c = w * 2 + i;
            const size_t gb = gbB + (size_t)(kt * 8 + c) * 128 + lane;
            gld_lds16(Bsw + gb * 8, &Bl[b][(c * 64) * 8]);
        }
    };

    stage(0, 0);
    stage(1, 1);
    for (int kt = 0; kt < 16; ++kt) {
        if (kt < 15) asm volatile("s_waitcnt vmcnt(6)" ::: "memory");
        else         asm volatile("s_waitcnt vmcnt(0)" ::: "memory");
        __builtin_amdgcn_s_barrier();
        asm volatile("" ::: "memory");
        const int b = kt & 1;
        #pragma unroll
        for (int kk = 0; kk < 2; ++kk) {
            const int kc = kk * 4 + qd;
            s16x8 a[4], bb[2];
            #pragma unroll
            for (int mt = 0; mt < 4; ++mt)
                a[mt] = *(const s16x8*)&Al[b][(kc * 128 + mw + mt * 16 + ln) * 8];
            #pragma unroll
            for (int nt = 0; nt < 2; ++nt)
                bb[nt] = *(const s16x8*)&Bl[b][(kc * 64 + nw + nt * 16 + ln) * 8];
            #pragma unroll
            for (int mt = 0; mt < 4; ++mt)
                #pragma unroll
                for (int nt = 0; nt < 2; ++nt)
                    acc[mt][nt] = __builtin_amdgcn_mfma_f32_16x16x32_bf16(a[mt], bb[nt], acc[mt][nt], 0, 0, 0);
        }
        if (kt < 14) {
            __builtin_amdgcn_s_barrier();
            asm volatile("" ::: "memory");
            stage(kt + 2, b);
        }
    }

    #pragma unroll
    for (int mt = 0; mt < 4; ++mt)
        #pragma unroll
        for (int nt = 0; nt < 2; ++nt)
            #pragma unroll
            for (int i = 0; i < 4; ++i) {
                const int m = m0 + mw + mt * 16 + qd * 4 + i;
                const int n = n0 + nw + nt * 16 + ln;
                outF[(size_t)m * 1024 + n] = acc[mt][nt][i];
            }
}

// Flash attention v5 (R13, kept): 4 waves x 32q, 32x32x16 MFMA, 3-buffer LDS DMA,
// 2-tile lookahead, counted vmcnt across raw s_barrier. XCD-swizzled block ids.
__device__ __forceinline__ void fa_compute(
        const unsigned short* Ksb, const unsigned short* Vsb,
        const int H, const int l31, const s16x8* qf,
        f32x16v* accO, float& ls0, float& ls1, float& ls2, float& ls3) {
    f32x16v accS[2] = {};
    #pragma unroll
    for (int kk = 0; kk < 4; ++kk) {
        s16x8 kf0 = *(const s16x8*)&Ksb[((kk * 2 + H) * 64 + l31) * 8];
        s16x8 kf1 = *(const s16x8*)&Ksb[((kk * 2 + H) * 64 + 32 + l31) * 8];
        accS[0] = __builtin_amdgcn_mfma_f32_32x32x16_bf16(kf0, qf[kk], accS[0], 0, 0, 0);
        accS[1] = __builtin_amdgcn_mfma_f32_32x32x16_bf16(kf1, qf[kk], accS[1], 0, 0, 0);
    }

    u32x4v af[4];
    #pragma unroll
    for (int mt = 0; mt < 2; ++mt) {
        float p[16];
        #pragma unroll
        for (int r = 0; r < 16; ++r)
            p[r] = exp2f(accS[mt][r]);
        #pragma unroll
        for (int r = 0; r < 16; r += 4) {
            ls0 += p[r + 0]; ls1 += p[r + 1]; ls2 += p[r + 2]; ls3 += p[r + 3];
        }
        unsigned int C[8];
        #pragma unroll
        for (int j = 0; j < 8; ++j)
            asm("v_cvt_pk_bf16_f32 %0, %1, %2" : "=v"(C[j]) : "v"(p[2 * j]), "v"(p[2 * j + 1]));
        #pragma unroll
        for (int pp = 0; pp < 2; ++pp) {
            unsigned int x0 = C[4 * pp + 0], y0 = C[4 * pp + 2];
            unsigned int x1 = C[4 * pp + 1], y1 = C[4 * pp + 3];
            asm("v_permlane32_swap_b32 %0, %1" : "+v"(x0), "+v"(y0));
            asm("v_permlane32_swap_b32 %0, %1" : "+v"(x1), "+v"(y1));
            u32x4v a; a.x = x0; a.y = x1; a.z = y0; a.w = y1;
            af[mt * 2 + pp] = a;
        }
    }

    #pragma unroll
    for (int kk2 = 0; kk2 < 4; ++kk2) {
        s16x8 a = __builtin_bit_cast(s16x8, af[kk2]);
        s16x8 vf0 = *(const s16x8*)&Vsb[((kk2 * 2 + H) * 64 + l31) * 8];
        s16x8 vf1 = *(const s16x8*)&Vsb[((kk2 * 2 + H) * 64 + 32 + l31) * 8];
        accO[0] = __builtin_amdgcn_mfma_f32_32x32x16_bf16(a, vf0, accO[0], 0, 0, 0);
        accO[1] = __builtin_amdgcn_mfma_f32_32x32x16_bf16(a, vf1, accO[1], 0, 0, 0);
    }
}

__global__ __launch_bounds__(256, 2)
void fattn(const unsigned short* __restrict__ Q, const unsigned short* __restrict__ Ksw,
           const unsigned short* __restrict__ Vsw, unsigned short* __restrict__ ctx) {
    __shared__ __align__(16) unsigned short Ks3[3][512 * 8];
    __shared__ __align__(16) unsigned short Vs3[3][512 * 8];

    const int t = threadIdx.x, lane = t & 63, w = t >> 6;
    const int l31 = lane & 31, H = lane >> 5;
    const int bid = blockIdx.x + (blockIdx.y << 4);
    const int wid = (bid & 7) * 64 + (bid >> 3);
    const int bh = wid >> 4, m0 = (wid & 15) * 128;
    const size_t head = (size_t)bh * 2048 * 64;

    s16x8 qf[4];
    #pragma unroll
    for (int kk = 0; kk < 4; ++kk)
        qf[kk] = *(const s16x8*)(Q + head + (size_t)(m0 + w * 32 + l31) * 64 + kk * 16 + H * 8);
    asm volatile("s_waitcnt vmcnt(0)" ::: "memory");
    #pragma unroll
    for (int kk = 0; kk < 4; ++kk) {
        u32x4v q = __builtin_bit_cast(u32x4v, qf[kk]);
        asm volatile("" : "+v"(q.x), "+v"(q.y), "+v"(q.z), "+v"(q.w));
        qf[kk] = __builtin_bit_cast(s16x8, q);
    }

    const size_t tb = (size_t)bh * 32 * 512;
    {
        #pragma unroll
        for (int kt = 0; kt < 2; ++kt)
            #pragma unroll
            for (int j = 0; j < 2; ++j) {
                gld_lds16(Ksw + (tb + kt * 512 + j * 256 + t) * 8, &Ks3[kt][(j * 256 + w * 64) * 8]);
                gld_lds16(Vsw + (tb + kt * 512 + j * 256 + t) * 8, &Vs3[kt][(j * 256 + w * 64) * 8]);
            }
    }

    f32x16v accO[2] = {};
    float ls0 = 0.f, ls1 = 0.f, ls2 = 0.f, ls3 = 0.f;

    int cur = 0;
    for (int kt = 0; kt < 31; ++kt) {
        asm volatile("s_waitcnt vmcnt(4)" ::: "memory");
        __builtin_amdgcn_s_barrier();
        asm volatile("" ::: "memory");
        if (kt < 30) {
            const int ib = (cur == 0) ? 2 : cur - 1;
            const size_t tbn = tb + (size_t)(kt + 2) * 512;
            #pragma unroll
            for (int j = 0; j < 2; ++j) {
                gld_lds16(Ksw + (tbn + j * 256 + t) * 8, &Ks3[ib][(j * 256 + w * 64) * 8]);
                gld_lds16(Vsw + (tbn + j * 256 + t) * 8, &Vs3[ib][(j * 256 + w * 64) * 8]);
            }
        }
        fa_compute(Ks3[cur], Vs3[cur], H, l31, qf, accO, ls0, ls1, ls2, ls3);
        cur = (cur == 2) ? 0 : cur + 1;
    }
    asm volatile("s_waitcnt vmcnt(0)" ::: "memory");
    __builtin_amdgcn_s_barrier();
    asm volatile("" ::: "memory");
    fa_compute(Ks3[cur], Vs3[cur], H, l31, qf, accO, ls0, ls1, ls2, ls3);

    float lsum = (ls0 + ls1) + (ls2 + ls3);
    lsum += __shfl_xor(lsum, 32, 64);
    const float inv = 1.f / lsum;

    #pragma unroll
    for (int r = 0; r < 16; ++r) {
        const int qloc = (r & 3) + 8 * (r >> 2) + 4 * H;
        const float rinv = __shfl(inv, qloc, 64);
        const int mrow = (bh >> 4) * 2048 + m0 + w * 32 + qloc;
        #pragma unroll
        for (int nt = 0; nt < 2; ++nt) {
            const int k = (bh & 15) * 64 + nt * 32 + l31;
            const size_t g = ((size_t)(mrow >> 7) * 128 + (k >> 3)) * 128 + (mrow & 127);
            ctx[g * 8 + (k & 7)] = f2bf(accO[nt][r] * rinv);
        }
    }
}

extern "C" void kernel_launch(void* const* d_in, const int* in_sizes, int n_in,
                              void* d_out, int out_size, void* d_ws, size_t ws_size,
                              hipStream_t stream) {
    char* ws = (char*)d_ws;
    unsigned short* Qb  = (unsigned short*)(ws);
    unsigned short* Ksw = (unsigned short*)(ws + ((size_t)8 << 20));
    unsigned short* Vsw = (unsigned short*)(ws + ((size_t)16 << 20));
    unsigned short* Wqt = (unsigned short*)(ws + ((size_t)24 << 20));
    unsigned short* Wkt = (unsigned short*)(ws + ((size_t)26 << 20));
    unsigned short* Wvt = (unsigned short*)(ws + ((size_t)28 << 20));
    unsigned short* Aq  = (unsigned short*)(ws + ((size_t)30 << 20));
    unsigned short* Ak  = (unsigned short*)(ws + ((size_t)38 << 20));
    unsigned short* Av  = (unsigned short*)(ws + ((size_t)46 << 20));
    unsigned short* ctx = (unsigned short*)(ws + ((size_t)24 << 20));  // after QKV GEMM
    unsigned short* Wot = (unsigned short*)(ws);                        // after fattn (Qb dead)

    const bool big = ws_size >= ((size_t)54 << 20);

    cvt3<<<dim3(16, 16, 3), 256, 0, stream>>>((const float*)d_in[3], (const float*)d_in[4],
                                              (const float*)d_in[5], Wqt, Wkt, Wvt);

    if (big) {
        cvtA<<<dim3(16, 32, 3), 256, 0, stream>>>((const float*)d_in[0], (const float*)d_in[1],
                                                  (const float*)d_in[2], Aq, Ak, Av);
        gemm_qkv<<<dim3(768), 256, 0, stream>>>(Aq, Ak, Av, Wqt, Wkt, Wvt,
                                                Qb, Ksw, Vsw, 0.125f * 1.44269504f);
    } else {
        gemm_qkv_pack<<<dim3(8, 32, 3), 256, 0, stream>>>(
            (const float*)d_in[0], (const float*)d_in[1], (const float*)d_in[2],
            Wqt, Wkt, Wvt, Qb, Ksw, Vsw, 0.125f * 1.44269504f);
    }

    fattn<<<dim3(16, 32), dim3(256), 0, stream>>>(Qb, Ksw, Vsw, ctx);

    cvt3<<<dim3(16, 16, 1), 256, 0, stream>>>((const float*)d_in[6], nullptr, nullptr,
                                              Wot, nullptr, nullptr);

    gemm_out<<<dim3(512), 256, 0, stream>>>(ctx, Wot, (float*)d_out);
}

// Round 8
// 225.730 us; speedup vs baseline: 1.2326x; 1.0323x over previous
//
#include <hip/hip_runtime.h>
#include <hip/hip_bf16.h>

// MHA: B=2, S=2048, D=1024, H=16, HD=64. fp32 in, fp32 out.
// Swizzled bf16 inter-kernel layouts (16B blocks) so all staging is contiguous DMA:
//   A/W swizzle ([R][K=1024]): block g=((r>>7)*128+(k>>3))*128+(r&127)
//   K_sw/V_sw: block g=((bh*32+kt)*8+kc)*64+row
// ws (>=54MB proven by R14 big path): [0,8)MB Qb | [8,16) Ksw | [16,24) Vsw |
//   [24,30) Wq/k/vt | [30,38) Aq | [38,46) Ak | [46,54) Av.
//   ctx overlays [24,32) after QKV GEMM; Opart [32,48) + Lpart [48,48.5) overlay
//   dead Aq/Ak/Av during fattn; Wot overlays [0,2) after fattn (Qb dead).
// Q-proj scale folds 1/sqrt(HD)*log2(e) so fattn uses native exp2.
// R9:  fattn swapped-QK^T/permlane structure: latency-bound at 2 waves/SIMD.
// R10: PV pipelining null -> within-wave scheduling not the constraint.
// R11/R12: XCD swizzle PROVEN (FETCH 70->12MB), reg-loads regressed (exposed latency).
// R13: 3-buf counted-vmcnt fattn: 65us. R14: DMA-GEMMs: total 241->233us.
// R15: fattn KV-split=2 (flash-decoding): grid 1024 (8 XCD x 128), 2-buffer 32KB LDS,
//   two-barrier counted-vmcnt, launch_bounds(256,4) -> 4 waves/SIMD (2x TLP).
//   Partial O (bf16 reg-dump) + partial rowsums -> fa_comb combines/divides/writes ctx.
//   Rowsum via MFMA ones-B: accL[r] = rowsum(q=crow(r,H)) at the exact (lane,reg) the
//   epilogue needs. R16 = R15 resubmit (infra 'container failed twice', audit clean:
//   Opart/Lpart in-bounds, vmcnt ledger exact, barriers uniform, no spill at 4/CU).

typedef short s16x8 __attribute__((ext_vector_type(8)));
typedef float f32x4v __attribute__((ext_vector_type(4)));
typedef float f32x16v __attribute__((ext_vector_type(16)));
typedef unsigned int u32x4v __attribute__((ext_vector_type(4)));

__device__ inline unsigned short f2bf(float f) {   // RNE (proven R2-R6)
    union { float f; unsigned int i; } x; x.f = f;
    unsigned int r = x.i + 0x7FFFu + ((x.i >> 16) & 1u);
    return (unsigned short)(r >> 16);
}
__device__ inline unsigned int pkbf(float lo, float hi) {  // lo16=bf(lo), hi16=bf(hi)
    return (unsigned int)f2bf(lo) | ((unsigned int)f2bf(hi) << 16);
}
__device__ inline float bf2f(unsigned short u) {
    union { unsigned int i; float f; } x; x.i = (unsigned int)u << 16; return x.f;
}

// async global->LDS, 16B/lane. Global address PER-LANE; LDS base wave-uniform,
// HW writes base + lane*16.
__device__ inline void gld_lds16(const unsigned short* g, unsigned short* l) {
    __builtin_amdgcn_global_load_lds(
        (const __attribute__((address_space(1))) unsigned int*)(const void*)g,
        (__attribute__((address_space(3))) unsigned int*)(void*)l,
        16, 0, 0);
}

// W[K=1024][N=1024] fp32 -> Wt bf16 in A/W swizzle (transpose+convert). z selects tensor.
__global__ __launch_bounds__(256)
void cvt3(const float* __restrict__ W0, const float* __restrict__ W1, const float* __restrict__ W2,
          unsigned short* __restrict__ T0, unsigned short* __restrict__ T1, unsigned short* __restrict__ T2) {
    const float* W = (blockIdx.z == 0) ? W0 : (blockIdx.z == 1) ? W1 : W2;
    unsigned short* Wt = (blockIdx.z == 0) ? T0 : (blockIdx.z == 1) ? T1 : T2;
    __shared__ __align__(16) unsigned short Ls[64 * 72];
    const int t = threadIdx.x;
    const int k0 = blockIdx.y * 64, n0 = blockIdx.x * 64;
    const int r = t >> 4, c4 = (t & 15) * 4;
    #pragma unroll
    for (int i = 0; i < 4; ++i) {
        float4 wv = *(const float4*)&W[(size_t)(k0 + r + i * 16) * 1024 + n0 + c4];
        Ls[(c4 + 0) * 72 + r + i * 16] = f2bf(wv.x);
        Ls[(c4 + 1) * 72 + r + i * 16] = f2bf(wv.y);
        Ls[(c4 + 2) * 72 + r + i * 16] = f2bf(wv.z);
        Ls[(c4 + 3) * 72 + r + i * 16] = f2bf(wv.w);
    }
    __syncthreads();
    #pragma unroll
    for (int i = 0; i < 2; ++i) {
        const int p = i * 256 + t;
        const int n = p & 63, kc = p >> 6;
        s16x8 v = *(const s16x8*)&Ls[n * 72 + kc * 8];
        const int gn = n0 + n, k = k0 + kc * 8;
        const size_t g = ((size_t)(gn >> 7) * 128 + (k >> 3)) * 128 + (gn & 127);
        *(s16x8*)&Wt[g * 8] = v;
    }
}

// A[4096][1024] fp32 -> bf16 A/W swizzle (no transpose). Grid (16 k-tiles, 32 rp, 3 z).
__global__ __launch_bounds__(256)
void cvtA(const float* __restrict__ A0, const float* __restrict__ A1, const float* __restrict__ A2,
          unsigned short* __restrict__ O0, unsigned short* __restrict__ O1, unsigned short* __restrict__ O2) {
    const float* A = (blockIdx.z == 0) ? A0 : (blockIdx.z == 1) ? A1 : A2;
    unsigned short* O = (blockIdx.z == 0) ? O0 : (blockIdx.z == 1) ? O1 : O2;
    __shared__ __align__(16) unsigned short Ls[8192];   // 16 KB
    const int t = threadIdx.x;
    const int k0 = blockIdx.x * 64, rp = blockIdx.y;
    const int row = t >> 1, kh = (t & 1) * 32;
    const float* src = A + (size_t)(rp * 128 + row) * 1024 + k0 + kh;
    float4 f[8];
    #pragma unroll
    for (int i = 0; i < 8; ++i) f[i] = ((const float4*)src)[i];
    #pragma unroll
    for (int j = 0; j < 4; ++j) {
        uint4 u;
        u.x = pkbf(f[j * 2].x, f[j * 2].y);
        u.y = pkbf(f[j * 2].z, f[j * 2].w);
        u.z = pkbf(f[j * 2 + 1].x, f[j * 2 + 1].y);
        u.w = pkbf(f[j * 2 + 1].z, f[j * 2 + 1].w);
        const int kc = (t & 1) * 4 + j;
        *(uint4*)&Ls[(kc * 128 + row) * 8] = u;
    }
    __syncthreads();
    const size_t gbase = ((size_t)rp * 128 + (k0 >> 3)) * 128;
    #pragma unroll
    for (int i = 0; i < 4; ++i) {
        const int idx = i * 256 + t;
        *(uint4*)&O[(gbase + idx) * 8] = *(const uint4*)&Ls[idx * 8];
    }
}

// QKV GEMM: C = A_bf16 @ W^T, both operands DMA. 128x128 tile, BK=32, 32KB LDS,
// 3 blocks/CU, grid 768 = one round, XCD chunk 96, 2-buffer counted vmcnt(4).
__global__ __launch_bounds__(256, 3)
void gemm_qkv(const unsigned short* __restrict__ Aq, const unsigned short* __restrict__ Ak,
              const unsigned short* __restrict__ Av,
              const unsigned short* __restrict__ W0, const unsigned short* __restrict__ W1,
              const unsigned short* __restrict__ W2,
              unsigned short* __restrict__ OQ, unsigned short* __restrict__ OK,
              unsigned short* __restrict__ OV, float scaleQ) {
    const int p = blockIdx.x;
    const int L = (p & 7) * 96 + (p >> 3);          // 768 = 8 XCD x 96
    const int z = L >> 8;
    const int rem = L & 255;
    const int m0 = (rem >> 3) * 128, n0 = (rem & 7) * 128;
    const unsigned short* Asw = (z == 0) ? Aq : (z == 1) ? Ak : Av;
    const unsigned short* Bsw = (z == 0) ? W0 : (z == 1) ? W1 : W2;
    const float scale = (z == 0) ? scaleQ : 1.0f;

    __shared__ __align__(16) unsigned short Al[2][4096];
    __shared__ __align__(16) unsigned short Bl[2][4096];
    const int t = threadIdx.x, lane = t & 63, w = t >> 6;
    const int ln = lane & 15, qd = lane >> 4;
    const int mw = (w & 1) * 64, nw = (w >> 1) * 64;
    const size_t gaB = (size_t)(m0 >> 7) * 16384;
    const size_t gbB = (size_t)(n0 >> 7) * 16384;

    f32x4v acc[4][4] = {};

    auto stage = [&](int kt, int b) {
        const size_t ga = gaB + (size_t)kt * 512;
        const size_t gb = gbB + (size_t)kt * 512;
        #pragma unroll
        for (int j = 0; j < 2; ++j)
            gld_lds16(Asw + (ga + j * 256 + t) * 8, &Al[b][(j * 256 + w * 64) * 8]);
        #pragma unroll
        for (int j = 0; j < 2; ++j)
            gld_lds16(Bsw + (gb + j * 256 + t) * 8, &Bl[b][(j * 256 + w * 64) * 8]);
    };

    stage(0, 0);
    stage(1, 1);
    for (int kt = 0; kt < 32; ++kt) {
        if (kt < 31) asm volatile("s_waitcnt vmcnt(4)" ::: "memory");
        else         asm volatile("s_waitcnt vmcnt(0)" ::: "memory");
        __builtin_amdgcn_s_barrier();
        asm volatile("" ::: "memory");
        const int b = kt & 1;
        {
            s16x8 a[4], bb[4];
            #pragma unroll
            for (int mt = 0; mt < 4; ++mt)
                a[mt] = *(const s16x8*)&Al[b][(qd * 128 + mw + mt * 16 + ln) * 8];
            #pragma unroll
            for (int nt = 0; nt < 4; ++nt)
                bb[nt] = *(const s16x8*)&Bl[b][(qd * 128 + nw + nt * 16 + ln) * 8];
            #pragma unroll
            for (int mt = 0; mt < 4; ++mt)
                #pragma unroll
                for (int nt = 0; nt < 4; ++nt)
                    acc[mt][nt] = __builtin_amdgcn_mfma_f32_16x16x32_bf16(a[mt], bb[nt], acc[mt][nt], 0, 0, 0);
        }
        if (kt < 30) {
            __builtin_amdgcn_s_barrier();
            asm volatile("" ::: "memory");
            stage(kt + 2, b);
        }
    }

    #pragma unroll
    for (int mt = 0; mt < 4; ++mt)
        #pragma unroll
        for (int nt = 0; nt < 4; ++nt)
            #pragma unroll
            for (int i = 0; i < 4; ++i) {
                const int m = m0 + mw + mt * 16 + qd * 4 + i;
                const int n = n0 + nw + nt * 16 + ln;
                const float v = acc[mt][nt][i] * scale;
                const int bh = (m >> 11) * 16 + (n >> 6), s = m & 2047, hd = n & 63;
                if (z == 0) {
                    OQ[((size_t)bh * 2048 + s) * 64 + hd] = f2bf(v);
                } else if (z == 1) {
                    const size_t g = ((size_t)(bh * 32 + (s >> 6)) * 8 + (hd >> 3)) * 64 + (s & 63);
                    OK[g * 8 + (hd & 7)] = f2bf(v);
                } else {
                    const size_t g = ((size_t)(bh * 32 + (s >> 6)) * 8 + ((s >> 3) & 7)) * 64 + hd;
                    OV[g * 8 + (s & 7)] = f2bf(v);
                }
            }
}

// Output GEMM: out = ctx_sw @ Wot^T. 128x64 tile, BK=64, 2-buffer counted vmcnt(6).
__global__ __launch_bounds__(256, 2)
void gemm_out(const unsigned short* __restrict__ Asw, const unsigned short* __restrict__ Bsw,
              float* __restrict__ outF) {
    const int p = blockIdx.x;
    const int L = (p & 7) * 64 + (p >> 3);          // 512 = 8 XCD x 64
    const int m0 = (L >> 4) * 128, n0 = (L & 15) * 64;

    __shared__ __align__(16) unsigned short Al[2][8192];
    __shared__ __align__(16) unsigned short Bl[2][4096];
    const int t = threadIdx.x, lane = t & 63, w = t >> 6;
    const int ln = lane & 15, qd = lane >> 4;
    const int mw = (w & 1) * 64, nw = (w >> 1) * 32;
    const size_t gaB = (size_t)(m0 >> 7) * 16384;
    const size_t gbB = (size_t)(n0 >> 7) * 16384 + (n0 & 127);

    f32x4v acc[4][2] = {};

    auto stage = [&](int kt, int b) {
        const size_t ga = gaB + (size_t)kt * 1024;
        #pragma unroll
        for (int j = 0; j < 4; ++j)
            gld_lds16(Asw + (ga + j * 256 + t) * 8, &Al[b][(j * 256 + w * 64) * 8]);
        #pragma unroll
        for (int i = 0; i < 2; ++i) {
            const int c = w * 2 + i;
            const size_t gb = gbB + (size_t)(kt * 8 + c) * 128 + lane;
            gld_lds16(Bsw + gb * 8, &Bl[b][(c * 64) * 8]);
        }
    };

    stage(0, 0);
    stage(1, 1);
    for (int kt = 0; kt < 16; ++kt) {
        if (kt < 15) asm volatile("s_waitcnt vmcnt(6)" ::: "memory");
        else         asm volatile("s_waitcnt vmcnt(0)" ::: "memory");
        __builtin_amdgcn_s_barrier();
        asm volatile("" ::: "memory");
        const int b = kt & 1;
        #pragma unroll
        for (int kk = 0; kk < 2; ++kk) {
            const int kc = kk * 4 + qd;
            s16x8 a[4], bb[2];
            #pragma unroll
            for (int mt = 0; mt < 4; ++mt)
                a[mt] = *(const s16x8*)&Al[b][(kc * 128 + mw + mt * 16 + ln) * 8];
            #pragma unroll
            for (int nt = 0; nt < 2; ++nt)
                bb[nt] = *(const s16x8*)&Bl[b][(kc * 64 + nw + nt * 16 + ln) * 8];
            #pragma unroll
            for (int mt = 0; mt < 4; ++mt)
                #pragma unroll
                for (int nt = 0; nt < 2; ++nt)
                    acc[mt][nt] = __builtin_amdgcn_mfma_f32_16x16x32_bf16(a[mt], bb[nt], acc[mt][nt], 0, 0, 0);
        }
        if (kt < 14) {
            __builtin_amdgcn_s_barrier();
            asm volatile("" ::: "memory");
            stage(kt + 2, b);
        }
    }

    #pragma unroll
    for (int mt = 0; mt < 4; ++mt)
        #pragma unroll
        for (int nt = 0; nt < 2; ++nt)
            #pragma unroll
            for (int i = 0; i < 4; ++i) {
                const int m = m0 + mw + mt * 16 + qd * 4 + i;
                const int n = n0 + nw + nt * 16 + ln;
                outF[(size_t)m * 1024 + n] = acc[mt][nt][i];
            }
}

// Flash attention v6 (KV-split): per tile, S^T = K Q^T (swapped), P = 2^S packed via
// cvt_pk+permlane, O += P V, rowsum via MFMA against all-ones B (lands at the exact
// (lane,reg) the epilogue needs: accL[r] = rowsum(q=crow(r,H)), any l31).
__device__ __forceinline__ void fa_compute(
        const unsigned short* Ksb, const unsigned short* Vsb,
        const int H, const int l31, const s16x8* qf,
        f32x16v* accO, f32x16v& accL) {
    f32x16v accS[2] = {};
    #pragma unroll
    for (int kk = 0; kk < 4; ++kk) {
        s16x8 kf0 = *(const s16x8*)&Ksb[((kk * 2 + H) * 64 + l31) * 8];
        s16x8 kf1 = *(const s16x8*)&Ksb[((kk * 2 + H) * 64 + 32 + l31) * 8];
        accS[0] = __builtin_amdgcn_mfma_f32_32x32x16_bf16(kf0, qf[kk], accS[0], 0, 0, 0);
        accS[1] = __builtin_amdgcn_mfma_f32_32x32x16_bf16(kf1, qf[kk], accS[1], 0, 0, 0);
    }

    u32x4v af[4];
    #pragma unroll
    for (int mt = 0; mt < 2; ++mt) {
        float p[16];
        #pragma unroll
        for (int r = 0; r < 16; ++r)
            p[r] = exp2f(accS[mt][r]);
        unsigned int C[8];
        #pragma unroll
        for (int j = 0; j < 8; ++j)
            asm("v_cvt_pk_bf16_f32 %0, %1, %2" : "=v"(C[j]) : "v"(p[2 * j]), "v"(p[2 * j + 1]));
        #pragma unroll
        for (int pp = 0; pp < 2; ++pp) {
            unsigned int x0 = C[4 * pp + 0], y0 = C[4 * pp + 2];
            unsigned int x1 = C[4 * pp + 1], y1 = C[4 * pp + 3];
            asm("v_permlane32_swap_b32 %0, %1" : "+v"(x0), "+v"(y0));
            asm("v_permlane32_swap_b32 %0, %1" : "+v"(x1), "+v"(y1));
            u32x4v a; a.x = x0; a.y = x1; a.z = y0; a.w = y1;
            af[mt * 2 + pp] = a;
        }
    }

    const s16x8 ones = {(short)0x3F80, (short)0x3F80, (short)0x3F80, (short)0x3F80,
                        (short)0x3F80, (short)0x3F80, (short)0x3F80, (short)0x3F80};
    #pragma unroll
    for (int kk2 = 0; kk2 < 4; ++kk2) {
        s16x8 a = __builtin_bit_cast(s16x8, af[kk2]);
        s16x8 vf0 = *(const s16x8*)&Vsb[((kk2 * 2 + H) * 64 + l31) * 8];
        s16x8 vf1 = *(const s16x8*)&Vsb[((kk2 * 2 + H) * 64 + 32 + l31) * 8];
        accO[0] = __builtin_amdgcn_mfma_f32_32x32x16_bf16(a, vf0, accO[0], 0, 0, 0);
        accO[1] = __builtin_amdgcn_mfma_f32_32x32x16_bf16(a, vf1, accO[1], 0, 0, 0);
        accL    = __builtin_amdgcn_mfma_f32_32x32x16_bf16(a, ones, accL, 0, 0, 0);
    }
}

// Grid 1024 = 8 XCD x 128 (4 heads/XCD). Each block: 128 q-rows x 16 kt tiles
// (half the KV range). 2-buffer 32KB LDS, two-barrier counted vmcnt(4), 4 blocks/CU.
__global__ __launch_bounds__(256, 4)
void fattn_sp(const unsigned short* __restrict__ Q, const unsigned short* __restrict__ Ksw,
              const unsigned short* __restrict__ Vsw, unsigned short* __restrict__ Opart,
              float* __restrict__ Lpart) {
    __shared__ __align__(16) unsigned short Ks2[2][4096];
    __shared__ __align__(16) unsigned short Vs2[2][4096];

    const int t = threadIdx.x, lane = t & 63, w = t >> 6;
    const int l31 = lane & 31, H = lane >> 5;
    const int bid = blockIdx.x;
    const int wid = (bid & 7) * 128 + (bid >> 3);   // 1024 = 8 XCD x 128
    const int bh = wid >> 5, inner = wid & 31;
    const int split = inner >> 4, mblk = inner & 15;
    const int m0 = mblk * 128;
    const size_t head = (size_t)bh * 2048 * 64;

    s16x8 qf[4];
    #pragma unroll
    for (int kk = 0; kk < 4; ++kk)
        qf[kk] = *(const s16x8*)(Q + head + (size_t)(m0 + w * 32 + l31) * 64 + kk * 16 + H * 8);
    asm volatile("s_waitcnt vmcnt(0)" ::: "memory");
    #pragma unroll
    for (int kk = 0; kk < 4; ++kk) {
        u32x4v q = __builtin_bit_cast(u32x4v, qf[kk]);
        asm volatile("" : "+v"(q.x), "+v"(q.y), "+v"(q.z), "+v"(q.w));
        qf[kk] = __builtin_bit_cast(s16x8, q);
    }

    const size_t tb = (size_t)(bh * 32 + split * 16) * 512;
    auto stage = [&](int kt, int b) {   // 4 vm-ops per wave
        const size_t tk = tb + (size_t)kt * 512;
        #pragma unroll
        for (int j = 0; j < 2; ++j)
            gld_lds16(Ksw + (tk + j * 256 + t) * 8, &Ks2[b][(j * 256 + w * 64) * 8]);
        #pragma unroll
        for (int j = 0; j < 2; ++j)
            gld_lds16(Vsw + (tk + j * 256 + t) * 8, &Vs2[b][(j * 256 + w * 64) * 8]);
    };

    stage(0, 0);
    stage(1, 1);

    f32x16v accO[2] = {};
    f32x16v accL = {};

    for (int kt = 0; kt < 16; ++kt) {
        if (kt < 15) asm volatile("s_waitcnt vmcnt(4)" ::: "memory");
        else         asm volatile("s_waitcnt vmcnt(0)" ::: "memory");
        __builtin_amdgcn_s_barrier();
        asm volatile("" ::: "memory");
        fa_compute(Ks2[kt & 1], Vs2[kt & 1], H, l31, qf, accO, accL);
        if (kt < 14) {
            __builtin_amdgcn_s_barrier();   // all waves done reading buf kt&1
            asm volatile("" ::: "memory");
            stage(kt + 2, kt & 1);
        }
    }

    // dump partials: accO as bf16 (per-thread 64B), accL f32 (per (w,H), lanes l31==0)
    const int lb = bh * 16 + mblk;
    unsigned int Wd[16];
    #pragma unroll
    for (int nt = 0; nt < 2; ++nt)
        #pragma unroll
        for (int r = 0; r < 16; r += 2)
            Wd[nt * 8 + r / 2] = pkbf(accO[nt][r], accO[nt][r + 1]);
    uint4* od = (uint4*)(Opart + ((size_t)(split * 512 + lb) * 256 + t) * 32);
    od[0] = *(const uint4*)&Wd[0];
    od[1] = *(const uint4*)&Wd[4];
    od[2] = *(const uint4*)&Wd[8];
    od[3] = *(const uint4*)&Wd[12];
    if (l31 == 0) {
        float lv[16];
        #pragma unroll
        for (int r = 0; r < 16; ++r) lv[r] = accL[r];
        float4* ld = (float4*)(Lpart + (((size_t)(split * 512 + lb) * 4 + w) * 2 + H) * 16);
        ld[0] = *(const float4*)&lv[0];
        ld[1] = *(const float4*)&lv[4];
        ld[2] = *(const float4*)&lv[8];
        ld[3] = *(const float4*)&lv[12];
    }
}

// Combine: ctx = (O0 + O1) / (L0 + L1), written in A/W swizzle. Grid 512 x 256.
__global__ __launch_bounds__(256)
void fa_comb(const unsigned short* __restrict__ Opart, const float* __restrict__ Lpart,
             unsigned short* __restrict__ ctx) {
    const int lb = blockIdx.x, t = threadIdx.x;
    const int lane = t & 63, w = t >> 6;
    const int l31 = lane & 31, H = lane >> 5;
    const int bh = lb >> 4, m0 = (lb & 15) * 128;

    const float* L0 = Lpart + (((size_t)lb * 4 + w) * 2 + H) * 16;
    const float* L1 = Lpart + (((size_t)(512 + lb) * 4 + w) * 2 + H) * 16;
    float inv[16];
    #pragma unroll
    for (int r = 0; r < 16; ++r) inv[r] = 1.f / (L0[r] + L1[r]);

    const uint4* o0 = (const uint4*)(Opart + ((size_t)lb * 256 + t) * 32);
    const uint4* o1 = (const uint4*)(Opart + ((size_t)(512 + lb) * 256 + t) * 32);
    unsigned int A0[16], A1[16];
    *(uint4*)&A0[0] = o0[0]; *(uint4*)&A0[4] = o0[1];
    *(uint4*)&A0[8] = o0[2]; *(uint4*)&A0[12] = o0[3];
    *(uint4*)&A1[0] = o1[0]; *(uint4*)&A1[4] = o1[1];
    *(uint4*)&A1[8] = o1[2]; *(uint4*)&A1[12] = o1[3];

    #pragma unroll
    for (int r = 0; r < 16; ++r) {
        const int qloc = (r & 3) + 8 * (r >> 2) + 4 * H;
        const int mrow = (bh >> 4) * 2048 + m0 + w * 32 + qloc;
        #pragma unroll
        for (int nt = 0; nt < 2; ++nt) {
            const int j = nt * 16 + r;
            const unsigned int w0 = A0[j >> 1], w1 = A1[j >> 1];
            const unsigned short h0 = (j & 1) ? (unsigned short)(w0 >> 16) : (unsigned short)(w0 & 0xFFFF);
            const unsigned short h1 = (j & 1) ? (unsigned short)(w1 >> 16) : (unsigned short)(w1 & 0xFFFF);
            const float out = (bf2f(h0) + bf2f(h1)) * inv[r];
            const int k = (bh & 15) * 64 + nt * 32 + l31;
            const size_t g = ((size_t)(mrow >> 7) * 128 + (k >> 3)) * 128 + (mrow & 127);
            ctx[g * 8 + (k & 7)] = f2bf(out);
        }
    }
}

extern "C" void kernel_launch(void* const* d_in, const int* in_sizes, int n_in,
                              void* d_out, int out_size, void* d_ws, size_t ws_size,
                              hipStream_t stream) {
    char* ws = (char*)d_ws;
    unsigned short* Qb    = (unsigned short*)(ws);
    unsigned short* Ksw   = (unsigned short*)(ws + ((size_t)8 << 20));
    unsigned short* Vsw   = (unsigned short*)(ws + ((size_t)16 << 20));
    unsigned short* Wqt   = (unsigned short*)(ws + ((size_t)24 << 20));
    unsigned short* Wkt   = (unsigned short*)(ws + ((size_t)26 << 20));
    unsigned short* Wvt   = (unsigned short*)(ws + ((size_t)28 << 20));
    unsigned short* Aq    = (unsigned short*)(ws + ((size_t)30 << 20));
    unsigned short* Ak    = (unsigned short*)(ws + ((size_t)38 << 20));
    unsigned short* Av    = (unsigned short*)(ws + ((size_t)46 << 20));
    unsigned short* ctx   = (unsigned short*)(ws + ((size_t)24 << 20));  // after QKV GEMM
    unsigned short* Opart = (unsigned short*)(ws + ((size_t)32 << 20));  // overlays dead Aq/Ak
    float*          Lpart = (float*)         (ws + ((size_t)48 << 20));  // overlays dead Av
    unsigned short* Wot   = (unsigned short*)(ws);                        // after fattn (Qb dead)

    cvt3<<<dim3(16, 16, 3), 256, 0, stream>>>((const float*)d_in[3], (const float*)d_in[4],
                                              (const float*)d_in[5], Wqt, Wkt, Wvt);

    cvtA<<<dim3(16, 32, 3), 256, 0, stream>>>((const float*)d_in[0], (const float*)d_in[1],
                                              (const float*)d_in[2], Aq, Ak, Av);
    gemm_qkv<<<dim3(768), 256, 0, stream>>>(Aq, Ak, Av, Wqt, Wkt, Wvt,
                                            Qb, Ksw, Vsw, 0.125f * 1.44269504f);

    fattn_sp<<<dim3(1024), 256, 0, stream>>>(Qb, Ksw, Vsw, Opart, Lpart);
    fa_comb<<<dim3(512), 256, 0, stream>>>(Opart, Lpart, ctx);

    cvt3<<<dim3(16, 16, 1), 256, 0, stream>>>((const float*)d_in[6], nullptr, nullptr,
                                              Wot, nullptr, nullptr);

    gemm_out<<<dim3(512), 256, 0, stream>>>(ctx, Wot, (float*)d_out);
}